// Round 10
// baseline (2479.082 us; speedup 1.0000x reference)
//
#include <hip/hip_runtime.h>
#include <hip/hip_bf16.h>
#include <math.h>

#define N_PTS 16384
#define KNN_K 32
#define CAP 512            // per-query filtered candidate list capacity
#define HDIM 128
#define TSAMP 4096         // tau sample: first TSAMP rows (subset order-stat bound)
#define NSLICE 4

typedef __attribute__((ext_vector_type(8))) short bf16x8;
typedef __attribute__((ext_vector_type(8))) unsigned short us8;
typedef __attribute__((ext_vector_type(4))) float f32x4;

// ---------------------------------------------------------------------------
// numpy-pairwise fp32 sum of squares per row (np.sum(x*x, axis=1) replica).
template<int C>
__global__ void sqnorm_np_kernel(const float* __restrict__ feat, float* __restrict__ sq) {
  int r = blockIdx.x * 256 + threadIdx.x;
  if (r >= N_PTS) return;
  const float* xr = feat + (size_t)r * C;
  float acc[8];
  #pragma unroll
  for (int j = 0; j < 8; j++) acc[j] = __fmul_rn(xr[j], xr[j]);
  for (int i = 8; i < C; i += 8) {
    #pragma unroll
    for (int j = 0; j < 8; j++)
      acc[j] = __fadd_rn(acc[j], __fmul_rn(xr[i + j], xr[i + j]));
  }
  float s01 = __fadd_rn(acc[0], acc[1]);
  float s23 = __fadd_rn(acc[2], acc[3]);
  float s45 = __fadd_rn(acc[4], acc[5]);
  float s67 = __fadd_rn(acc[6], acc[7]);
  sq[r] = __fadd_rn(__fadd_rn(s01, s23), __fadd_rn(s45, s67));
}

// ---------------------------------------------------------------------------
// hi/lo bf16 split with XOR chunk swizzle baked into the global layout.
template<int C>
__global__ void split_swz_kernel(const float* __restrict__ x, unsigned short* __restrict__ hi,
                                 unsigned short* __restrict__ lo) {
  constexpr int CH = C / 8;
  int gid = blockIdx.x * 256 + threadIdx.x;    // N*CH threads
  int n = gid / CH, c = gid & (CH - 1);
  if (n >= N_PTS) return;
  const float* src = x + (size_t)n * C + c * 8;
  unsigned short h8[8], l8[8];
  #pragma unroll
  for (int j = 0; j < 8; j++) {
    float v = src[j];
    __hip_bfloat16 h = __float2bfloat16(v);
    float hf = __bfloat162float(h);
    __hip_bfloat16 l = __float2bfloat16(v - hf);
    h8[j] = *(unsigned short*)&h;
    l8[j] = *(unsigned short*)&l;
  }
  size_t o = (size_t)n * C + (size_t)(((c ^ (n & (CH - 1)))) * 8);
  *(us8*)(hi + o) = *(const us8*)h8;
  *(us8*)(lo + o) = *(const us8*)l8;
}

// ---------------------------------------------------------------------------
// KNN pass A (tau, sampled) — unchanged from round 9 (known good, ~260 us).
template<int C>
__launch_bounds__(512)
__global__ void knn_tau(const unsigned short* __restrict__ xhi,
                        const unsigned short* __restrict__ xlo,
                        const float* __restrict__ sq,
                        float margin, float* __restrict__ tau) {
  constexpr int CH = C / 8, KC = C / 32;
  constexpr int NB = 32 * C * 2;
  constexpr int SEGS = (2 * NB) / 16 / 512;
  __shared__ unsigned char Bs[2 * NB];
  __shared__ float tred[64][65];
  const int t = threadIdx.x;
  const int qbase = blockIdx.x * 64;
  const int wv = t >> 6, lane = t & 63, qd = lane >> 4, l16 = lane & 15;
  const int mi = (wv & 3) * 16, ni = (wv >> 2) * 16;

  bf16x8 ah[KC], al[KC];
  {
    const int arow = qbase + mi + l16;
    const int akey = arow & (CH - 1);
    #pragma unroll
    for (int kc = 0; kc < KC; kc++) {
      size_t o = (size_t)arow * C + (size_t)(((kc * 4 + qd) ^ akey) * 8);
      ah[kc] = *(const bf16x8*)(xhi + o);
      al[kc] = *(const bf16x8*)(xlo + o);
    }
  }
  int qr[4];
  #pragma unroll
  for (int r = 0; r < 4; r++) qr[r] = qbase + mi + qd * 4 + r;
  float t0[4], t1[4];
  #pragma unroll
  for (int r = 0; r < 4; r++) { t0[r] = INFINITY; t1[r] = INFINITY; }

  const int brow = ni + l16;
  const int bkey = brow & (CH - 1);

  us8 regs[SEGS];
  #pragma unroll
  for (int s = 0; s < SEGS; s++) {
    int boff = (t + s * 512) * 16;
    int mtx = boff >= NB;
    int off = boff & (NB - 1);
    regs[s] = *(const us8*)((mtx ? xlo : xhi) + off / 2);
  }
  for (int ti = 0; ti < TSAMP / 32; ti++) {
    __syncthreads();
    #pragma unroll
    for (int s = 0; s < SEGS; s++) {
      int boff = (t + s * 512) * 16;
      int mtx = boff >= NB;
      int off = boff & (NB - 1);
      *(us8*)&Bs[mtx * NB + off] = regs[s];
    }
    __syncthreads();
    if (ti + 1 < TSAMP / 32) {
      #pragma unroll
      for (int s = 0; s < SEGS; s++) {
        int boff = (t + s * 512) * 16;
        int mtx = boff >= NB;
        int off = boff & (NB - 1);
        regs[s] = *(const us8*)((mtx ? xlo : xhi) + (size_t)(ti + 1) * 32 * C + off / 2);
      }
    }
    f32x4 acc = {0.f, 0.f, 0.f, 0.f};
    #pragma unroll
    for (int kc = 0; kc < KC; kc++) {
      size_t bo = (size_t)brow * (2 * C) + (size_t)(((kc * 4 + qd) ^ bkey) * 16);
      bf16x8 bh = *(const bf16x8*)&Bs[bo];
      bf16x8 bl = *(const bf16x8*)&Bs[NB + bo];
      acc = __builtin_amdgcn_mfma_f32_16x16x32_bf16(ah[kc], bh, acc, 0, 0, 0);
      acc = __builtin_amdgcn_mfma_f32_16x16x32_bf16(ah[kc], bl, acc, 0, 0, 0);
      acc = __builtin_amdgcn_mfma_f32_16x16x32_bf16(al[kc], bh, acc, 0, 0, 0);
    }
    const int j = ti * 32 + ni + l16;
    const float sj = sq[j];
    #pragma unroll
    for (int r = 0; r < 4; r++) {
      float d = fmaf(-2.f, acc[r], sj);
      if (d < t1[r] && j != qr[r]) {
        bool lt = d < t0[r];
        t1[r] = lt ? t0[r] : d;
        t0[r] = lt ? d : t0[r];
      }
    }
  }
  const int strm = ni + l16;
  #pragma unroll
  for (int r = 0; r < 4; r++) {
    tred[mi + qd * 4 + r][strm]      = t0[r];
    tred[mi + qd * 4 + r][32 + strm] = t1[r];
  }
  __syncthreads();
  const int tq = t >> 3, i0 = (t & 7) * 8;
  #pragma unroll
  for (int ii = 0; ii < 8; ii++) {
    const int i = i0 + ii;
    const float vi = tred[tq][i];
    int rank = 0;
    for (int m = 0; m < 64; m++) {
      float vm = tred[tq][m];
      rank += (vm < vi || (vm == vi && m < i)) ? 1 : 0;
    }
    if (rank == 32) tau[qbase + tq] = vi + margin;
  }
}

// ---------------------------------------------------------------------------
// KNN pass B (filter v2): 128 queries/block; each wave computes TWO 16x16
// output tiles (mi and mi+64) per j-tile -> 24 MFMA per barrier period and
// half the blocks/periods of round 9. Same per-(q,j) MFMA order -> d values
// bit-identical; candidate set identical.
template<int C>
__launch_bounds__(512)
__global__ void knn_filter(const unsigned short* __restrict__ xhi,
                           const unsigned short* __restrict__ xlo,
                           const float* __restrict__ sq,
                           const float* __restrict__ tau,
                           int* __restrict__ cnt, int* __restrict__ list) {
  constexpr int CH = C / 8, KC = C / 32;
  constexpr int NB = 32 * C * 2;
  constexpr int SEGS = (2 * NB) / 16 / 512;
  constexpr int JSPAN = N_PTS / NSLICE;
  __shared__ unsigned char Bs[2 * NB];
  const int t = threadIdx.x;
  const int qbase = blockIdx.x * 128;
  const int jbase = blockIdx.y * JSPAN;
  const int wv = t >> 6, lane = t & 63, qd = lane >> 4, l16 = lane & 15;
  const int ni = (wv & 1) * 16;
  const int mi0 = (wv >> 1) * 16;          // wave also handles mi0 + 64

  bf16x8 ah[2][KC], al[2][KC];
  #pragma unroll
  for (int h = 0; h < 2; h++) {
    const int arow = qbase + mi0 + h * 64 + l16;
    const int akey = arow & (CH - 1);
    #pragma unroll
    for (int kc = 0; kc < KC; kc++) {
      size_t o = (size_t)arow * C + (size_t)(((kc * 4 + qd) ^ akey) * 8);
      ah[h][kc] = *(const bf16x8*)(xhi + o);
      al[h][kc] = *(const bf16x8*)(xlo + o);
    }
  }
  int qr[2][4]; float tq[2][4];
  #pragma unroll
  for (int h = 0; h < 2; h++)
    #pragma unroll
    for (int r = 0; r < 4; r++) {
      qr[h][r] = qbase + mi0 + h * 64 + qd * 4 + r;
      tq[h][r] = tau[qr[h][r]];
    }
  const int brow = ni + l16;
  const int bkey = brow & (CH - 1);

  us8 regs[SEGS];
  #pragma unroll
  for (int s = 0; s < SEGS; s++) {
    int boff = (t + s * 512) * 16;
    int mtx = boff >= NB;
    int off = boff & (NB - 1);
    regs[s] = *(const us8*)((mtx ? xlo : xhi) + (size_t)jbase * C + off / 2);
  }
  for (int ti = 0; ti < JSPAN / 32; ti++) {
    __syncthreads();
    #pragma unroll
    for (int s = 0; s < SEGS; s++) {
      int boff = (t + s * 512) * 16;
      int mtx = boff >= NB;
      int off = boff & (NB - 1);
      *(us8*)&Bs[mtx * NB + off] = regs[s];
    }
    __syncthreads();
    if (ti + 1 < JSPAN / 32) {
      #pragma unroll
      for (int s = 0; s < SEGS; s++) {
        int boff = (t + s * 512) * 16;
        int mtx = boff >= NB;
        int off = boff & (NB - 1);
        regs[s] = *(const us8*)((mtx ? xlo : xhi) + (size_t)(jbase + (ti + 1) * 32) * C + off / 2);
      }
    }
    f32x4 acc0 = {0.f, 0.f, 0.f, 0.f};
    f32x4 acc1 = {0.f, 0.f, 0.f, 0.f};
    #pragma unroll
    for (int kc = 0; kc < KC; kc++) {
      size_t bo = (size_t)brow * (2 * C) + (size_t)(((kc * 4 + qd) ^ bkey) * 16);
      bf16x8 bh = *(const bf16x8*)&Bs[bo];
      bf16x8 bl = *(const bf16x8*)&Bs[NB + bo];
      acc0 = __builtin_amdgcn_mfma_f32_16x16x32_bf16(ah[0][kc], bh, acc0, 0, 0, 0);
      acc0 = __builtin_amdgcn_mfma_f32_16x16x32_bf16(ah[0][kc], bl, acc0, 0, 0, 0);
      acc0 = __builtin_amdgcn_mfma_f32_16x16x32_bf16(al[0][kc], bh, acc0, 0, 0, 0);
      acc1 = __builtin_amdgcn_mfma_f32_16x16x32_bf16(ah[1][kc], bh, acc1, 0, 0, 0);
      acc1 = __builtin_amdgcn_mfma_f32_16x16x32_bf16(ah[1][kc], bl, acc1, 0, 0, 0);
      acc1 = __builtin_amdgcn_mfma_f32_16x16x32_bf16(al[1][kc], bh, acc1, 0, 0, 0);
    }
    const int j = jbase + ti * 32 + ni + l16;
    const float sj = sq[j];
    #pragma unroll
    for (int r = 0; r < 4; r++) {
      float d0 = fmaf(-2.f, acc0[r], sj);
      if (d0 <= tq[0][r] && j != qr[0][r]) {
        int pos = atomicAdd(&cnt[qr[0][r]], 1);
        if (pos < CAP) list[(size_t)qr[0][r] * CAP + pos] = j;
      }
      float d1 = fmaf(-2.f, acc1[r], sj);
      if (d1 <= tq[1][r] && j != qr[1][r]) {
        int pos = atomicAdd(&cnt[qr[1][r]], 1);
        if (pos < CAP) list[(size_t)qr[1][r] * CAP + pos] = j;
      }
    }
  }
}

__global__ void zero_cnt_kernel(int* __restrict__ cnt) {
  cnt[blockIdx.x * 256 + threadIdx.x] = 0;
}

// ---------------------------------------------------------------------------
// KNN refine v2 (np-fp32-exact, arithmetic unchanged): one 256-thread block
// per query. Candidate rows staged into LDS in 64-row chunks with coalesced
// loads (+1-float row pad -> conflict-free), then thread t runs the IDENTICAL
// sequential fp32 fma chain from LDS. Rank by (d, index) = top_k order.
template<int C>
__launch_bounds__(256)
__global__ void knn_refine_np(const float* __restrict__ feat, const float* __restrict__ sq,
                              const int* __restrict__ cnt, const int* __restrict__ list,
                              int* __restrict__ idx_out) {
  __shared__ float rows[64 * (C + 1)];
  __shared__ float xqs[C];
  __shared__ float ds[CAP];
  __shared__ int   js[CAP];
  __shared__ int   jl[64];
  __shared__ float sjl[64];
  const int q = blockIdx.x;
  const int t = threadIdx.x;  // 256
  for (int v = t; v < C; v += 256) xqs[v] = feat[(size_t)q * C + v];
  int cq = cnt[q]; if (cq > CAP) cq = CAP;
  const float sqq = sq[q];

  for (int base = 0; base < cq; base += 64) {
    const int nc = (cq - base < 64) ? (cq - base) : 64;
    __syncthreads();                       // jl/rows free (prev chunk done)
    if (t < nc) {
      int j = list[(size_t)q * CAP + base + t];
      jl[t] = j;
      sjl[t] = sq[j];
    }
    __syncthreads();
    for (int v = t; v < nc * C; v += 256) {
      int r = v >> ((C == 64) ? 6 : 7);
      int c = v & (C - 1);
      rows[r * (C + 1) + c] = feat[(size_t)jl[r] * C + c];
    }
    __syncthreads();
    if (t < nc) {
      float g = 0.f;
      const float* row = &rows[t * (C + 1)];
      for (int c = 0; c < C; c++) g = fmaf(xqs[c], row[c], g);
      ds[base + t] = __fsub_rn(__fadd_rn(sqq, sjl[t]), __fmul_rn(2.f, g));
      js[base + t] = jl[t];
    }
  }
  __syncthreads();
  for (int e = t; e < cq; e += 256) {
    float d = ds[e]; int j = js[e];
    int rank = 0;
    for (int m = 0; m < cq; m++) {
      float dm = ds[m]; int jm = js[m];
      if (dm < d || (dm == d && jm < j)) rank++;
    }
    if (rank < KNN_K) idx_out[(size_t)q * KNN_K + rank] = j;
  }
}

// ---------------------------------------------------------------------------
// P[n][ch] = b[ch] + x[n]@(Wtop - Wbot)[:,ch];  Q[n][ch] = x[n]@Wbot[:,ch].
template<int C>
__global__ void pq_kernel(const float* __restrict__ feat, const float* __restrict__ W,
                          const float* __restrict__ b, float* __restrict__ P,
                          float* __restrict__ Q) {
  int gid = blockIdx.x * 256 + threadIdx.x;   // N*128 threads
  int n = gid >> 7, ch = gid & 127;
  const float* xr = feat + (size_t)n * C;
  double p = (double)b[ch], q = 0.0;
  for (int d = 0; d < C; d++) {
    double xv = (double)xr[d];
    p += xv * (double)W[(size_t)d * HDIM + ch];
    q += xv * (double)W[(size_t)(C + d) * HDIM + ch];
  }
  P[gid] = (float)(p - q);
  Q[gid] = (float)q;
}

// ---------------------------------------------------------------------------
__global__ void edge_gather2(const float* __restrict__ P, const float* __restrict__ Q,
                             const int* __restrict__ idx, float* __restrict__ hmax,
                             float* __restrict__ hmin, double* __restrict__ stats) {
  __shared__ double red0[256];
  __shared__ double red1[256];
  const int t = threadIdx.x;
  const int ch = t & 127, half = t >> 7;
  const size_t nb = (size_t)blockIdx.x * 16 + (size_t)half * 8;
  double s = 0.0, s2 = 0.0;
  for (int u = 0; u < 8; u++) {
    const size_t n = nb + u;
    double p = (double)P[n * 128 + ch];
    double mx = -1.0e300, mn = 1.0e300;
    for (int k = 0; k < KNN_K; k++) {
      int j = idx[n * KNN_K + k];
      double h = p + (double)Q[(size_t)j * 128 + ch];
      h = h > 0.0 ? h : 0.0;
      mx = h > mx ? h : mx;
      mn = h < mn ? h : mn;
      s += h; s2 += h * h;
    }
    hmax[n * 128 + ch] = (float)mx;
    hmin[n * 128 + ch] = (float)mn;
  }
  red0[t] = s; red1[t] = s2;
  __syncthreads();
  if (t < 128) {
    atomicAdd(&stats[ch],       red0[t] + red0[t + 128]);
    atomicAdd(&stats[128 + ch], red1[t] + red1[t + 128]);
  }
}

__global__ void zero_stats_d(double* __restrict__ stats) {
  stats[threadIdx.x] = 0.0;
}

__global__ void bn_finalize_d(const double* __restrict__ stats, const float* __restrict__ g,
                              const float* __restrict__ beta, double* __restrict__ ss) {
  int ch = threadIdx.x;
  const double inv = 1.0 / ((double)N_PTS * (double)KNN_K);
  double mu = stats[ch] * inv;
  double var = stats[128 + ch] * inv - mu * mu;
  double sc = (double)g[ch] / sqrt(var + 1e-5);
  ss[ch] = sc;
  ss[128 + ch] = (double)beta[ch] - mu * sc;
}

__global__ void ec_out_d(const float* __restrict__ hmax, const float* __restrict__ hmin,
                         const double* __restrict__ ss, float* __restrict__ h_f) {
  size_t i = (size_t)blockIdx.x * 256 + threadIdx.x;
  int ch = (int)(i & 127);
  double sc = ss[ch];
  double v = sc >= 0.0 ? (double)hmax[i] : (double)hmin[i];
  h_f[i] = (float)(v * sc + ss[128 + ch]);
}

// ---------------------------------------------------------------------------
__global__ void head1_kernel(const float* __restrict__ h2, const float* __restrict__ lw1,
                             const float* __restrict__ lb1, float* __restrict__ T) {
  int gid = blockIdx.x * 256 + threadIdx.x;
  int n = gid >> 6, hc = gid & 63;
  const float* hr = h2 + (size_t)n * 128;
  double a = (double)lb1[hc];
  for (int d = 0; d < 128; d++) {
    double v = (double)hr[d];
    v = v > 0.0 ? v : 0.0;
    a += v * (double)lw1[(size_t)d * 64 + hc];
  }
  T[gid] = (float)(a > 0.0 ? a : 0.0);
}

__global__ void head2_kernel(const float* __restrict__ T, const float* __restrict__ lw2,
                             const float* __restrict__ lb2, float* __restrict__ out) {
  int gid = blockIdx.x * 256 + threadIdx.x;
  int n = gid >> 6, oc = gid & 63;
  const float* tr = T + (size_t)n * 64;
  double a = (double)lb2[oc];
  for (int d = 0; d < 64; d++) a += (double)tr[d] * (double)lw2[(size_t)d * 64 + oc];
  out[gid] = (float)a;
}

// ---------------------------------------------------------------------------
extern "C" void kernel_launch(void* const* d_in, const int* in_sizes, int n_in,
                              void* d_out, int out_size, void* d_ws, size_t ws_size,
                              hipStream_t stream) {
  (void)in_sizes; (void)n_in; (void)out_size; (void)ws_size;
  const float* x     = (const float*)d_in[0];
  const float* W1    = (const float*)d_in[1];
  const float* b1    = (const float*)d_in[2];
  const float* g1    = (const float*)d_in[3];
  const float* beta1 = (const float*)d_in[4];
  const float* W2    = (const float*)d_in[5];
  const float* b2    = (const float*)d_in[6];
  const float* g2    = (const float*)d_in[7];
  const float* beta2 = (const float*)d_in[8];
  const float* lw1   = (const float*)d_in[9];
  const float* lb1   = (const float*)d_in[10];
  const float* lw2   = (const float*)d_in[11];
  const float* lb2   = (const float*)d_in[12];
  float* out = (float*)d_out;

  char* w = (char*)d_ws;
  size_t off = 0;
  auto alloc = [&](size_t bytes) { char* p = w + off; off += (bytes + 255) & ~(size_t)255; return p; };
  float*  sq    = (float*) alloc(N_PTS * 4);
  float*  tau   = (float*) alloc(N_PTS * 4);
  int*    cnt   = (int*)   alloc(N_PTS * 4);
  int*    list  = (int*)   alloc((size_t)N_PTS * CAP * 4);      // 32 MB
  int*    idx   = (int*)   alloc((size_t)N_PTS * KNN_K * 4);    //  2 MB
  unsigned short* xhi = (unsigned short*)alloc((size_t)N_PTS * HDIM * 2);
  unsigned short* xlo = (unsigned short*)alloc((size_t)N_PTS * HDIM * 2);
  float*  P     = (float*) alloc((size_t)N_PTS * HDIM * 4);
  float*  Q     = (float*) alloc((size_t)N_PTS * HDIM * 4);
  float*  hmax  = (float*) alloc((size_t)N_PTS * HDIM * 4);
  float*  hmin  = (float*) alloc((size_t)N_PTS * HDIM * 4);
  double* stats = (double*)alloc(2 * HDIM * 8);
  double* ss    = (double*)alloc(2 * HDIM * 8);
  float*  h1f   = (float*) alloc((size_t)N_PTS * HDIM * 4);
  float*  h2f   = P;        // reuse (P dead after gather2)
  float*  T     = Q;        // reuse (Q dead after gather2)

  // ---- stage 1: knn on x (C=64) ----
  sqnorm_np_kernel<64><<<N_PTS / 256, 256, 0, stream>>>(x, sq);
  split_swz_kernel<64><<<N_PTS * 8 / 256, 256, 0, stream>>>(x, xhi, xlo);
  knn_tau<64><<<N_PTS / 64, 512, 0, stream>>>(xhi, xlo, sq, 0.05f, tau);
  zero_cnt_kernel<<<N_PTS / 256, 256, 0, stream>>>(cnt);
  knn_filter<64><<<dim3(N_PTS / 128, NSLICE), 512, 0, stream>>>(xhi, xlo, sq, tau, cnt, list);
  knn_refine_np<64><<<N_PTS, 256, 0, stream>>>(x, sq, cnt, list, idx);

  // ---- edge conv 1 (fp64) ----
  pq_kernel<64><<<N_PTS * 128 / 256, 256, 0, stream>>>(x, W1, b1, P, Q);
  zero_stats_d<<<1, 256, 0, stream>>>(stats);
  edge_gather2<<<N_PTS / 16, 256, 0, stream>>>(P, Q, idx, hmax, hmin, stats);
  bn_finalize_d<<<1, 128, 0, stream>>>(stats, g1, beta1, ss);
  ec_out_d<<<N_PTS * HDIM / 256, 256, 0, stream>>>(hmax, hmin, ss, h1f);

  // ---- stage 2: knn on h1 (C=128) ----
  sqnorm_np_kernel<128><<<N_PTS / 256, 256, 0, stream>>>(h1f, sq);
  split_swz_kernel<128><<<N_PTS * 16 / 256, 256, 0, stream>>>(h1f, xhi, xlo);
  knn_tau<128><<<N_PTS / 64, 512, 0, stream>>>(xhi, xlo, sq, 0.2f, tau);
  zero_cnt_kernel<<<N_PTS / 256, 256, 0, stream>>>(cnt);
  knn_filter<128><<<dim3(N_PTS / 128, NSLICE), 512, 0, stream>>>(xhi, xlo, sq, tau, cnt, list);
  knn_refine_np<128><<<N_PTS, 256, 0, stream>>>(h1f, sq, cnt, list, idx);

  // ---- edge conv 2 (fp64) ----
  pq_kernel<128><<<N_PTS * 128 / 256, 256, 0, stream>>>(h1f, W2, b2, P, Q);
  zero_stats_d<<<1, 256, 0, stream>>>(stats);
  edge_gather2<<<N_PTS / 16, 256, 0, stream>>>(P, Q, idx, hmax, hmin, stats);
  bn_finalize_d<<<1, 128, 0, stream>>>(stats, g2, beta2, ss);
  ec_out_d<<<N_PTS * HDIM / 256, 256, 0, stream>>>(hmax, hmin, ss, h2f);

  // ---- head (fp64) ----
  head1_kernel<<<N_PTS * 64 / 256, 256, 0, stream>>>(h2f, lw1, lb1, T);
  head2_kernel<<<N_PTS * 64 / 256, 256, 0, stream>>>(T, lw2, lb2, out);
}

// Round 11
// 1737.230 us; speedup vs baseline: 1.4270x; 1.4270x over previous
//
#include <hip/hip_runtime.h>
#include <hip/hip_bf16.h>
#include <math.h>

#define N_PTS 16384
#define KNN_K 32
#define CAP 512            // per-query filtered candidate list capacity
#define HDIM 128
#define TSAMP 4096         // tau sample: first TSAMP rows (subset order-stat bound)
#define NSLICE 4
#define LBUF 128           // per-query LDS hit buffer (per slice-block)

typedef __attribute__((ext_vector_type(8))) short bf16x8;
typedef __attribute__((ext_vector_type(8))) unsigned short us8;
typedef __attribute__((ext_vector_type(4))) float f32x4;

// ---------------------------------------------------------------------------
// numpy-pairwise fp32 sum of squares per row (np.sum(x*x, axis=1) replica).
template<int C>
__global__ void sqnorm_np_kernel(const float* __restrict__ feat, float* __restrict__ sq) {
  int r = blockIdx.x * 256 + threadIdx.x;
  if (r >= N_PTS) return;
  const float* xr = feat + (size_t)r * C;
  float acc[8];
  #pragma unroll
  for (int j = 0; j < 8; j++) acc[j] = __fmul_rn(xr[j], xr[j]);
  for (int i = 8; i < C; i += 8) {
    #pragma unroll
    for (int j = 0; j < 8; j++)
      acc[j] = __fadd_rn(acc[j], __fmul_rn(xr[i + j], xr[i + j]));
  }
  float s01 = __fadd_rn(acc[0], acc[1]);
  float s23 = __fadd_rn(acc[2], acc[3]);
  float s45 = __fadd_rn(acc[4], acc[5]);
  float s67 = __fadd_rn(acc[6], acc[7]);
  sq[r] = __fadd_rn(__fadd_rn(s01, s23), __fadd_rn(s45, s67));
}

// ---------------------------------------------------------------------------
// hi/lo bf16 split with XOR chunk swizzle baked into the global layout.
template<int C>
__global__ void split_swz_kernel(const float* __restrict__ x, unsigned short* __restrict__ hi,
                                 unsigned short* __restrict__ lo) {
  constexpr int CH = C / 8;
  int gid = blockIdx.x * 256 + threadIdx.x;    // N*CH threads
  int n = gid / CH, c = gid & (CH - 1);
  if (n >= N_PTS) return;
  const float* src = x + (size_t)n * C + c * 8;
  unsigned short h8[8], l8[8];
  #pragma unroll
  for (int j = 0; j < 8; j++) {
    float v = src[j];
    __hip_bfloat16 h = __float2bfloat16(v);
    float hf = __bfloat162float(h);
    __hip_bfloat16 l = __float2bfloat16(v - hf);
    h8[j] = *(unsigned short*)&h;
    l8[j] = *(unsigned short*)&l;
  }
  size_t o = (size_t)n * C + (size_t)(((c ^ (n & (CH - 1)))) * 8);
  *(us8*)(hi + o) = *(const us8*)h8;
  *(us8*)(lo + o) = *(const us8*)l8;
}

// ---------------------------------------------------------------------------
// KNN pass A (tau, sampled) — unchanged (known good).
template<int C>
__launch_bounds__(512)
__global__ void knn_tau(const unsigned short* __restrict__ xhi,
                        const unsigned short* __restrict__ xlo,
                        const float* __restrict__ sq,
                        float margin, float* __restrict__ tau) {
  constexpr int CH = C / 8, KC = C / 32;
  constexpr int NB = 32 * C * 2;
  constexpr int SEGS = (2 * NB) / 16 / 512;
  __shared__ unsigned char Bs[2 * NB];
  __shared__ float tred[64][65];
  const int t = threadIdx.x;
  const int qbase = blockIdx.x * 64;
  const int wv = t >> 6, lane = t & 63, qd = lane >> 4, l16 = lane & 15;
  const int mi = (wv & 3) * 16, ni = (wv >> 2) * 16;

  bf16x8 ah[KC], al[KC];
  {
    const int arow = qbase + mi + l16;
    const int akey = arow & (CH - 1);
    #pragma unroll
    for (int kc = 0; kc < KC; kc++) {
      size_t o = (size_t)arow * C + (size_t)(((kc * 4 + qd) ^ akey) * 8);
      ah[kc] = *(const bf16x8*)(xhi + o);
      al[kc] = *(const bf16x8*)(xlo + o);
    }
  }
  int qr[4];
  #pragma unroll
  for (int r = 0; r < 4; r++) qr[r] = qbase + mi + qd * 4 + r;
  float t0[4], t1[4];
  #pragma unroll
  for (int r = 0; r < 4; r++) { t0[r] = INFINITY; t1[r] = INFINITY; }

  const int brow = ni + l16;
  const int bkey = brow & (CH - 1);

  us8 regs[SEGS];
  #pragma unroll
  for (int s = 0; s < SEGS; s++) {
    int boff = (t + s * 512) * 16;
    int mtx = boff >= NB;
    int off = boff & (NB - 1);
    regs[s] = *(const us8*)((mtx ? xlo : xhi) + off / 2);
  }
  for (int ti = 0; ti < TSAMP / 32; ti++) {
    __syncthreads();
    #pragma unroll
    for (int s = 0; s < SEGS; s++) {
      int boff = (t + s * 512) * 16;
      int mtx = boff >= NB;
      int off = boff & (NB - 1);
      *(us8*)&Bs[mtx * NB + off] = regs[s];
    }
    __syncthreads();
    if (ti + 1 < TSAMP / 32) {
      #pragma unroll
      for (int s = 0; s < SEGS; s++) {
        int boff = (t + s * 512) * 16;
        int mtx = boff >= NB;
        int off = boff & (NB - 1);
        regs[s] = *(const us8*)((mtx ? xlo : xhi) + (size_t)(ti + 1) * 32 * C + off / 2);
      }
    }
    f32x4 acc = {0.f, 0.f, 0.f, 0.f};
    #pragma unroll
    for (int kc = 0; kc < KC; kc++) {
      size_t bo = (size_t)brow * (2 * C) + (size_t)(((kc * 4 + qd) ^ bkey) * 16);
      bf16x8 bh = *(const bf16x8*)&Bs[bo];
      bf16x8 bl = *(const bf16x8*)&Bs[NB + bo];
      acc = __builtin_amdgcn_mfma_f32_16x16x32_bf16(ah[kc], bh, acc, 0, 0, 0);
      acc = __builtin_amdgcn_mfma_f32_16x16x32_bf16(ah[kc], bl, acc, 0, 0, 0);
      acc = __builtin_amdgcn_mfma_f32_16x16x32_bf16(al[kc], bh, acc, 0, 0, 0);
    }
    const int j = ti * 32 + ni + l16;
    const float sj = sq[j];
    #pragma unroll
    for (int r = 0; r < 4; r++) {
      float d = fmaf(-2.f, acc[r], sj);
      if (d < t1[r] && j != qr[r]) {
        bool lt = d < t0[r];
        t1[r] = lt ? t0[r] : d;
        t0[r] = lt ? d : t0[r];
      }
    }
  }
  const int strm = ni + l16;
  #pragma unroll
  for (int r = 0; r < 4; r++) {
    tred[mi + qd * 4 + r][strm]      = t0[r];
    tred[mi + qd * 4 + r][32 + strm] = t1[r];
  }
  __syncthreads();
  const int tq = t >> 3, i0 = (t & 7) * 8;
  #pragma unroll
  for (int ii = 0; ii < 8; ii++) {
    const int i = i0 + ii;
    const float vi = tred[tq][i];
    int rank = 0;
    for (int m = 0; m < 64; m++) {
      float vm = tred[tq][m];
      rank += (vm < vi || (vm == vi && m < i)) ? 1 : 0;
    }
    if (rank == 32) tau[qbase + tq] = vi + margin;
  }
}

// ---------------------------------------------------------------------------
// KNN pass B (filter v3): round-9 geometry (64 q/block, VGPR-lean) but hits
// append to per-query LDS buffers via LDS atomics (no global round-trip);
// one global atomicAdd per query at block end reserves a contiguous range,
// flushed with coalesced stores. Overflow spills to the old global path.
// Candidate SETS identical to round 9 -> output bit-identical.
template<int C>
__launch_bounds__(512)
__global__ void knn_filter(const unsigned short* __restrict__ xhi,
                           const unsigned short* __restrict__ xlo,
                           const float* __restrict__ sq,
                           const float* __restrict__ tau,
                           int* __restrict__ cnt, int* __restrict__ list) {
  constexpr int CH = C / 8, KC = C / 32;
  constexpr int NB = 32 * C * 2;
  constexpr int SEGS = (2 * NB) / 16 / 512;
  constexpr int JSPAN = N_PTS / NSLICE;
  __shared__ unsigned char Bs[2 * NB];
  __shared__ int lbuf[64 * LBUF];       // 32 KB
  __shared__ int lcnt[64];
  __shared__ int lbase[64];
  const int t = threadIdx.x;
  const int qbase = blockIdx.x * 64;
  const int jbase = blockIdx.y * JSPAN;
  const int wv = t >> 6, lane = t & 63, qd = lane >> 4, l16 = lane & 15;
  const int mi = (wv & 3) * 16, ni = (wv >> 2) * 16;

  if (t < 64) lcnt[t] = 0;

  bf16x8 ah[KC], al[KC];
  {
    const int arow = qbase + mi + l16;
    const int akey = arow & (CH - 1);
    #pragma unroll
    for (int kc = 0; kc < KC; kc++) {
      size_t o = (size_t)arow * C + (size_t)(((kc * 4 + qd) ^ akey) * 8);
      ah[kc] = *(const bf16x8*)(xhi + o);
      al[kc] = *(const bf16x8*)(xlo + o);
    }
  }
  int lq[4]; float tq[4];
  #pragma unroll
  for (int r = 0; r < 4; r++) {
    lq[r] = mi + qd * 4 + r;
    tq[r] = tau[qbase + lq[r]];
  }
  const int brow = ni + l16;
  const int bkey = brow & (CH - 1);

  us8 regs[SEGS];
  #pragma unroll
  for (int s = 0; s < SEGS; s++) {
    int boff = (t + s * 512) * 16;
    int mtx = boff >= NB;
    int off = boff & (NB - 1);
    regs[s] = *(const us8*)((mtx ? xlo : xhi) + (size_t)jbase * C + off / 2);
  }
  for (int ti = 0; ti < JSPAN / 32; ti++) {
    __syncthreads();                      // also covers lcnt init at ti==0
    #pragma unroll
    for (int s = 0; s < SEGS; s++) {
      int boff = (t + s * 512) * 16;
      int mtx = boff >= NB;
      int off = boff & (NB - 1);
      *(us8*)&Bs[mtx * NB + off] = regs[s];
    }
    __syncthreads();
    if (ti + 1 < JSPAN / 32) {
      #pragma unroll
      for (int s = 0; s < SEGS; s++) {
        int boff = (t + s * 512) * 16;
        int mtx = boff >= NB;
        int off = boff & (NB - 1);
        regs[s] = *(const us8*)((mtx ? xlo : xhi) + (size_t)(jbase + (ti + 1) * 32) * C + off / 2);
      }
    }
    f32x4 acc = {0.f, 0.f, 0.f, 0.f};
    #pragma unroll
    for (int kc = 0; kc < KC; kc++) {
      size_t bo = (size_t)brow * (2 * C) + (size_t)(((kc * 4 + qd) ^ bkey) * 16);
      bf16x8 bh = *(const bf16x8*)&Bs[bo];
      bf16x8 bl = *(const bf16x8*)&Bs[NB + bo];
      acc = __builtin_amdgcn_mfma_f32_16x16x32_bf16(ah[kc], bh, acc, 0, 0, 0);
      acc = __builtin_amdgcn_mfma_f32_16x16x32_bf16(ah[kc], bl, acc, 0, 0, 0);
      acc = __builtin_amdgcn_mfma_f32_16x16x32_bf16(al[kc], bh, acc, 0, 0, 0);
    }
    const int j = jbase + ti * 32 + ni + l16;
    const float sj = sq[j];
    #pragma unroll
    for (int r = 0; r < 4; r++) {
      float d = fmaf(-2.f, acc[r], sj);
      if (d <= tq[r] && j != qbase + lq[r]) {
        int pos = atomicAdd(&lcnt[lq[r]], 1);
        if (pos < LBUF) {
          lbuf[lq[r] * LBUF + pos] = j;
        } else {                          // rare overflow: direct global append
          int gp = atomicAdd(&cnt[qbase + lq[r]], 1);
          if (gp < CAP) list[(size_t)(qbase + lq[r]) * CAP + gp] = j;
        }
      }
    }
  }
  __syncthreads();
  if (t < 64) {
    int c = lcnt[t]; if (c > LBUF) c = LBUF;
    lcnt[t] = c;
    lbase[t] = atomicAdd(&cnt[qbase + t], c);
  }
  __syncthreads();
  for (int v = t; v < 64 * LBUF; v += 512) {
    int q = v >> 7, e = v & (LBUF - 1);   // LBUF == 128
    if (e < lcnt[q]) {
      int p = lbase[q] + e;
      if (p < CAP) list[(size_t)(qbase + q) * CAP + p] = lbuf[v];
    }
  }
}

__global__ void zero_cnt_kernel(int* __restrict__ cnt) {
  cnt[blockIdx.x * 256 + threadIdx.x] = 0;
}

// ---------------------------------------------------------------------------
// KNN refine (np-fp32-exact, LDS-staged; unchanged from round 10 — passed).
template<int C>
__launch_bounds__(256)
__global__ void knn_refine_np(const float* __restrict__ feat, const float* __restrict__ sq,
                              const int* __restrict__ cnt, const int* __restrict__ list,
                              int* __restrict__ idx_out) {
  __shared__ float rows[64 * (C + 1)];
  __shared__ float xqs[C];
  __shared__ float ds[CAP];
  __shared__ int   js[CAP];
  __shared__ int   jl[64];
  __shared__ float sjl[64];
  const int q = blockIdx.x;
  const int t = threadIdx.x;  // 256
  for (int v = t; v < C; v += 256) xqs[v] = feat[(size_t)q * C + v];
  int cq = cnt[q]; if (cq > CAP) cq = CAP;
  const float sqq = sq[q];

  for (int base = 0; base < cq; base += 64) {
    const int nc = (cq - base < 64) ? (cq - base) : 64;
    __syncthreads();
    if (t < nc) {
      int j = list[(size_t)q * CAP + base + t];
      jl[t] = j;
      sjl[t] = sq[j];
    }
    __syncthreads();
    for (int v = t; v < nc * C; v += 256) {
      int r = v >> ((C == 64) ? 6 : 7);
      int c = v & (C - 1);
      rows[r * (C + 1) + c] = feat[(size_t)jl[r] * C + c];
    }
    __syncthreads();
    if (t < nc) {
      float g = 0.f;
      const float* row = &rows[t * (C + 1)];
      for (int c = 0; c < C; c++) g = fmaf(xqs[c], row[c], g);
      ds[base + t] = __fsub_rn(__fadd_rn(sqq, sjl[t]), __fmul_rn(2.f, g));
      js[base + t] = jl[t];
    }
  }
  __syncthreads();
  for (int e = t; e < cq; e += 256) {
    float d = ds[e]; int j = js[e];
    int rank = 0;
    for (int m = 0; m < cq; m++) {
      float dm = ds[m]; int jm = js[m];
      if (dm < d || (dm == d && jm < j)) rank++;
    }
    if (rank < KNN_K) idx_out[(size_t)q * KNN_K + rank] = j;
  }
}

// ---------------------------------------------------------------------------
// P[n][ch] = b[ch] + x[n]@(Wtop - Wbot)[:,ch];  Q[n][ch] = x[n]@Wbot[:,ch].
template<int C>
__global__ void pq_kernel(const float* __restrict__ feat, const float* __restrict__ W,
                          const float* __restrict__ b, float* __restrict__ P,
                          float* __restrict__ Q) {
  int gid = blockIdx.x * 256 + threadIdx.x;   // N*128 threads
  int n = gid >> 7, ch = gid & 127;
  const float* xr = feat + (size_t)n * C;
  double p = (double)b[ch], q = 0.0;
  for (int d = 0; d < C; d++) {
    double xv = (double)xr[d];
    p += xv * (double)W[(size_t)d * HDIM + ch];
    q += xv * (double)W[(size_t)(C + d) * HDIM + ch];
  }
  P[gid] = (float)(p - q);
  Q[gid] = (float)q;
}

// ---------------------------------------------------------------------------
__global__ void edge_gather2(const float* __restrict__ P, const float* __restrict__ Q,
                             const int* __restrict__ idx, float* __restrict__ hmax,
                             float* __restrict__ hmin, double* __restrict__ stats) {
  __shared__ double red0[256];
  __shared__ double red1[256];
  const int t = threadIdx.x;
  const int ch = t & 127, half = t >> 7;
  const size_t nb = (size_t)blockIdx.x * 16 + (size_t)half * 8;
  double s = 0.0, s2 = 0.0;
  for (int u = 0; u < 8; u++) {
    const size_t n = nb + u;
    double p = (double)P[n * 128 + ch];
    double mx = -1.0e300, mn = 1.0e300;
    for (int k = 0; k < KNN_K; k++) {
      int j = idx[n * KNN_K + k];
      double h = p + (double)Q[(size_t)j * 128 + ch];
      h = h > 0.0 ? h : 0.0;
      mx = h > mx ? h : mx;
      mn = h < mn ? h : mn;
      s += h; s2 += h * h;
    }
    hmax[n * 128 + ch] = (float)mx;
    hmin[n * 128 + ch] = (float)mn;
  }
  red0[t] = s; red1[t] = s2;
  __syncthreads();
  if (t < 128) {
    atomicAdd(&stats[ch],       red0[t] + red0[t + 128]);
    atomicAdd(&stats[128 + ch], red1[t] + red1[t + 128]);
  }
}

__global__ void zero_stats_d(double* __restrict__ stats) {
  stats[threadIdx.x] = 0.0;
}

__global__ void bn_finalize_d(const double* __restrict__ stats, const float* __restrict__ g,
                              const float* __restrict__ beta, double* __restrict__ ss) {
  int ch = threadIdx.x;
  const double inv = 1.0 / ((double)N_PTS * (double)KNN_K);
  double mu = stats[ch] * inv;
  double var = stats[128 + ch] * inv - mu * mu;
  double sc = (double)g[ch] / sqrt(var + 1e-5);
  ss[ch] = sc;
  ss[128 + ch] = (double)beta[ch] - mu * sc;
}

__global__ void ec_out_d(const float* __restrict__ hmax, const float* __restrict__ hmin,
                         const double* __restrict__ ss, float* __restrict__ h_f) {
  size_t i = (size_t)blockIdx.x * 256 + threadIdx.x;
  int ch = (int)(i & 127);
  double sc = ss[ch];
  double v = sc >= 0.0 ? (double)hmax[i] : (double)hmin[i];
  h_f[i] = (float)(v * sc + ss[128 + ch]);
}

// ---------------------------------------------------------------------------
__global__ void head1_kernel(const float* __restrict__ h2, const float* __restrict__ lw1,
                             const float* __restrict__ lb1, float* __restrict__ T) {
  int gid = blockIdx.x * 256 + threadIdx.x;
  int n = gid >> 6, hc = gid & 63;
  const float* hr = h2 + (size_t)n * 128;
  double a = (double)lb1[hc];
  for (int d = 0; d < 128; d++) {
    double v = (double)hr[d];
    v = v > 0.0 ? v : 0.0;
    a += v * (double)lw1[(size_t)d * 64 + hc];
  }
  T[gid] = (float)(a > 0.0 ? a : 0.0);
}

__global__ void head2_kernel(const float* __restrict__ T, const float* __restrict__ lw2,
                             const float* __restrict__ lb2, float* __restrict__ out) {
  int gid = blockIdx.x * 256 + threadIdx.x;
  int n = gid >> 6, oc = gid & 63;
  const float* tr = T + (size_t)n * 64;
  double a = (double)lb2[oc];
  for (int d = 0; d < 64; d++) a += (double)tr[d] * (double)lw2[(size_t)d * 64 + oc];
  out[gid] = (float)a;
}

// ---------------------------------------------------------------------------
extern "C" void kernel_launch(void* const* d_in, const int* in_sizes, int n_in,
                              void* d_out, int out_size, void* d_ws, size_t ws_size,
                              hipStream_t stream) {
  (void)in_sizes; (void)n_in; (void)out_size; (void)ws_size;
  const float* x     = (const float*)d_in[0];
  const float* W1    = (const float*)d_in[1];
  const float* b1    = (const float*)d_in[2];
  const float* g1    = (const float*)d_in[3];
  const float* beta1 = (const float*)d_in[4];
  const float* W2    = (const float*)d_in[5];
  const float* b2    = (const float*)d_in[6];
  const float* g2    = (const float*)d_in[7];
  const float* beta2 = (const float*)d_in[8];
  const float* lw1   = (const float*)d_in[9];
  const float* lb1   = (const float*)d_in[10];
  const float* lw2   = (const float*)d_in[11];
  const float* lb2   = (const float*)d_in[12];
  float* out = (float*)d_out;

  char* w = (char*)d_ws;
  size_t off = 0;
  auto alloc = [&](size_t bytes) { char* p = w + off; off += (bytes + 255) & ~(size_t)255; return p; };
  float*  sq    = (float*) alloc(N_PTS * 4);
  float*  tau   = (float*) alloc(N_PTS * 4);
  int*    cnt   = (int*)   alloc(N_PTS * 4);
  int*    list  = (int*)   alloc((size_t)N_PTS * CAP * 4);      // 32 MB
  int*    idx   = (int*)   alloc((size_t)N_PTS * KNN_K * 4);    //  2 MB
  unsigned short* xhi = (unsigned short*)alloc((size_t)N_PTS * HDIM * 2);
  unsigned short* xlo = (unsigned short*)alloc((size_t)N_PTS * HDIM * 2);
  float*  P     = (float*) alloc((size_t)N_PTS * HDIM * 4);
  float*  Q     = (float*) alloc((size_t)N_PTS * HDIM * 4);
  float*  hmax  = (float*) alloc((size_t)N_PTS * HDIM * 4);
  float*  hmin  = (float*) alloc((size_t)N_PTS * HDIM * 4);
  double* stats = (double*)alloc(2 * HDIM * 8);
  double* ss    = (double*)alloc(2 * HDIM * 8);
  float*  h1f   = (float*) alloc((size_t)N_PTS * HDIM * 4);
  float*  h2f   = P;        // reuse (P dead after gather2)
  float*  T     = Q;        // reuse (Q dead after gather2)

  // ---- stage 1: knn on x (C=64) ----
  sqnorm_np_kernel<64><<<N_PTS / 256, 256, 0, stream>>>(x, sq);
  split_swz_kernel<64><<<N_PTS * 8 / 256, 256, 0, stream>>>(x, xhi, xlo);
  knn_tau<64><<<N_PTS / 64, 512, 0, stream>>>(xhi, xlo, sq, 0.05f, tau);
  zero_cnt_kernel<<<N_PTS / 256, 256, 0, stream>>>(cnt);
  knn_filter<64><<<dim3(N_PTS / 64, NSLICE), 512, 0, stream>>>(xhi, xlo, sq, tau, cnt, list);
  knn_refine_np<64><<<N_PTS, 256, 0, stream>>>(x, sq, cnt, list, idx);

  // ---- edge conv 1 (fp64) ----
  pq_kernel<64><<<N_PTS * 128 / 256, 256, 0, stream>>>(x, W1, b1, P, Q);
  zero_stats_d<<<1, 256, 0, stream>>>(stats);
  edge_gather2<<<N_PTS / 16, 256, 0, stream>>>(P, Q, idx, hmax, hmin, stats);
  bn_finalize_d<<<1, 128, 0, stream>>>(stats, g1, beta1, ss);
  ec_out_d<<<N_PTS * HDIM / 256, 256, 0, stream>>>(hmax, hmin, ss, h1f);

  // ---- stage 2: knn on h1 (C=128) ----
  sqnorm_np_kernel<128><<<N_PTS / 256, 256, 0, stream>>>(h1f, sq);
  split_swz_kernel<128><<<N_PTS * 16 / 256, 256, 0, stream>>>(h1f, xhi, xlo);
  knn_tau<128><<<N_PTS / 64, 512, 0, stream>>>(xhi, xlo, sq, 0.2f, tau);
  zero_cnt_kernel<<<N_PTS / 256, 256, 0, stream>>>(cnt);
  knn_filter<128><<<dim3(N_PTS / 64, NSLICE), 512, 0, stream>>>(xhi, xlo, sq, tau, cnt, list);
  knn_refine_np<128><<<N_PTS, 256, 0, stream>>>(h1f, sq, cnt, list, idx);

  // ---- edge conv 2 (fp64) ----
  pq_kernel<128><<<N_PTS * 128 / 256, 256, 0, stream>>>(h1f, W2, b2, P, Q);
  zero_stats_d<<<1, 256, 0, stream>>>(stats);
  edge_gather2<<<N_PTS / 16, 256, 0, stream>>>(P, Q, idx, hmax, hmin, stats);
  bn_finalize_d<<<1, 128, 0, stream>>>(stats, g2, beta2, ss);
  ec_out_d<<<N_PTS * HDIM / 256, 256, 0, stream>>>(hmax, hmin, ss, h2f);

  // ---- head (fp64) ----
  head1_kernel<<<N_PTS * 64 / 256, 256, 0, stream>>>(h2f, lw1, lb1, T);
  head2_kernel<<<N_PTS * 64 / 256, 256, 0, stream>>>(T, lw2, lb2, out);
}

// Round 12
// 1623.737 us; speedup vs baseline: 1.5268x; 1.0699x over previous
//
#include <hip/hip_runtime.h>
#include <hip/hip_bf16.h>
#include <math.h>

#define N_PTS 16384
#define KNN_K 32
#define CAP 512            // per-query filtered candidate list capacity
#define HDIM 128
#define TSAMP 4096         // tau sample: first TSAMP rows (subset order-stat bound)
#define NSLICE 4
#define LBUF 128           // per-query LDS hit buffer (per slice-block)

typedef __attribute__((ext_vector_type(8))) short bf16x8;
typedef __attribute__((ext_vector_type(8))) unsigned short us8;
typedef __attribute__((ext_vector_type(4))) float f32x4;

// ---------------------------------------------------------------------------
// numpy-pairwise fp32 sum of squares per row (np.sum(x*x, axis=1) replica).
template<int C>
__global__ void sqnorm_np_kernel(const float* __restrict__ feat, float* __restrict__ sq) {
  int r = blockIdx.x * 256 + threadIdx.x;
  if (r >= N_PTS) return;
  const float* xr = feat + (size_t)r * C;
  float acc[8];
  #pragma unroll
  for (int j = 0; j < 8; j++) acc[j] = __fmul_rn(xr[j], xr[j]);
  for (int i = 8; i < C; i += 8) {
    #pragma unroll
    for (int j = 0; j < 8; j++)
      acc[j] = __fadd_rn(acc[j], __fmul_rn(xr[i + j], xr[i + j]));
  }
  float s01 = __fadd_rn(acc[0], acc[1]);
  float s23 = __fadd_rn(acc[2], acc[3]);
  float s45 = __fadd_rn(acc[4], acc[5]);
  float s67 = __fadd_rn(acc[6], acc[7]);
  sq[r] = __fadd_rn(__fadd_rn(s01, s23), __fadd_rn(s45, s67));
}

// ---------------------------------------------------------------------------
// hi/lo bf16 split with XOR chunk swizzle baked into the global layout.
template<int C>
__global__ void split_swz_kernel(const float* __restrict__ x, unsigned short* __restrict__ hi,
                                 unsigned short* __restrict__ lo) {
  constexpr int CH = C / 8;
  int gid = blockIdx.x * 256 + threadIdx.x;    // N*CH threads
  int n = gid / CH, c = gid & (CH - 1);
  if (n >= N_PTS) return;
  const float* src = x + (size_t)n * C + c * 8;
  unsigned short h8[8], l8[8];
  #pragma unroll
  for (int j = 0; j < 8; j++) {
    float v = src[j];
    __hip_bfloat16 h = __float2bfloat16(v);
    float hf = __bfloat162float(h);
    __hip_bfloat16 l = __float2bfloat16(v - hf);
    h8[j] = *(unsigned short*)&h;
    l8[j] = *(unsigned short*)&l;
  }
  size_t o = (size_t)n * C + (size_t)(((c ^ (n & (CH - 1)))) * 8);
  *(us8*)(hi + o) = *(const us8*)h8;
  *(us8*)(lo + o) = *(const us8*)l8;
}

// ---------------------------------------------------------------------------
// KNN pass A (tau, sampled) — unchanged (known good).
template<int C>
__launch_bounds__(512)
__global__ void knn_tau(const unsigned short* __restrict__ xhi,
                        const unsigned short* __restrict__ xlo,
                        const float* __restrict__ sq,
                        float margin, float* __restrict__ tau) {
  constexpr int CH = C / 8, KC = C / 32;
  constexpr int NB = 32 * C * 2;
  constexpr int SEGS = (2 * NB) / 16 / 512;
  __shared__ unsigned char Bs[2 * NB];
  __shared__ float tred[64][65];
  const int t = threadIdx.x;
  const int qbase = blockIdx.x * 64;
  const int wv = t >> 6, lane = t & 63, qd = lane >> 4, l16 = lane & 15;
  const int mi = (wv & 3) * 16, ni = (wv >> 2) * 16;

  bf16x8 ah[KC], al[KC];
  {
    const int arow = qbase + mi + l16;
    const int akey = arow & (CH - 1);
    #pragma unroll
    for (int kc = 0; kc < KC; kc++) {
      size_t o = (size_t)arow * C + (size_t)(((kc * 4 + qd) ^ akey) * 8);
      ah[kc] = *(const bf16x8*)(xhi + o);
      al[kc] = *(const bf16x8*)(xlo + o);
    }
  }
  int qr[4];
  #pragma unroll
  for (int r = 0; r < 4; r++) qr[r] = qbase + mi + qd * 4 + r;
  float t0[4], t1[4];
  #pragma unroll
  for (int r = 0; r < 4; r++) { t0[r] = INFINITY; t1[r] = INFINITY; }

  const int brow = ni + l16;
  const int bkey = brow & (CH - 1);

  us8 regs[SEGS];
  #pragma unroll
  for (int s = 0; s < SEGS; s++) {
    int boff = (t + s * 512) * 16;
    int mtx = boff >= NB;
    int off = boff & (NB - 1);
    regs[s] = *(const us8*)((mtx ? xlo : xhi) + off / 2);
  }
  for (int ti = 0; ti < TSAMP / 32; ti++) {
    __syncthreads();
    #pragma unroll
    for (int s = 0; s < SEGS; s++) {
      int boff = (t + s * 512) * 16;
      int mtx = boff >= NB;
      int off = boff & (NB - 1);
      *(us8*)&Bs[mtx * NB + off] = regs[s];
    }
    __syncthreads();
    if (ti + 1 < TSAMP / 32) {
      #pragma unroll
      for (int s = 0; s < SEGS; s++) {
        int boff = (t + s * 512) * 16;
        int mtx = boff >= NB;
        int off = boff & (NB - 1);
        regs[s] = *(const us8*)((mtx ? xlo : xhi) + (size_t)(ti + 1) * 32 * C + off / 2);
      }
    }
    f32x4 acc = {0.f, 0.f, 0.f, 0.f};
    #pragma unroll
    for (int kc = 0; kc < KC; kc++) {
      size_t bo = (size_t)brow * (2 * C) + (size_t)(((kc * 4 + qd) ^ bkey) * 16);
      bf16x8 bh = *(const bf16x8*)&Bs[bo];
      bf16x8 bl = *(const bf16x8*)&Bs[NB + bo];
      acc = __builtin_amdgcn_mfma_f32_16x16x32_bf16(ah[kc], bh, acc, 0, 0, 0);
      acc = __builtin_amdgcn_mfma_f32_16x16x32_bf16(ah[kc], bl, acc, 0, 0, 0);
      acc = __builtin_amdgcn_mfma_f32_16x16x32_bf16(al[kc], bh, acc, 0, 0, 0);
    }
    const int j = ti * 32 + ni + l16;
    const float sj = sq[j];
    #pragma unroll
    for (int r = 0; r < 4; r++) {
      float d = fmaf(-2.f, acc[r], sj);
      if (d < t1[r] && j != qr[r]) {
        bool lt = d < t0[r];
        t1[r] = lt ? t0[r] : d;
        t0[r] = lt ? d : t0[r];
      }
    }
  }
  const int strm = ni + l16;
  #pragma unroll
  for (int r = 0; r < 4; r++) {
    tred[mi + qd * 4 + r][strm]      = t0[r];
    tred[mi + qd * 4 + r][32 + strm] = t1[r];
  }
  __syncthreads();
  const int tq = t >> 3, i0 = (t & 7) * 8;
  #pragma unroll
  for (int ii = 0; ii < 8; ii++) {
    const int i = i0 + ii;
    const float vi = tred[tq][i];
    int rank = 0;
    for (int m = 0; m < 64; m++) {
      float vm = tred[tq][m];
      rank += (vm < vi || (vm == vi && m < i)) ? 1 : 0;
    }
    if (rank == 32) tau[qbase + tq] = vi + margin;
  }
}

// ---------------------------------------------------------------------------
// KNN pass B (filter v3, unchanged from round 11 — LDS-atomic hit buffers).
template<int C>
__launch_bounds__(512)
__global__ void knn_filter(const unsigned short* __restrict__ xhi,
                           const unsigned short* __restrict__ xlo,
                           const float* __restrict__ sq,
                           const float* __restrict__ tau,
                           int* __restrict__ cnt, int* __restrict__ list) {
  constexpr int CH = C / 8, KC = C / 32;
  constexpr int NB = 32 * C * 2;
  constexpr int SEGS = (2 * NB) / 16 / 512;
  constexpr int JSPAN = N_PTS / NSLICE;
  __shared__ unsigned char Bs[2 * NB];
  __shared__ int lbuf[64 * LBUF];       // 32 KB
  __shared__ int lcnt[64];
  __shared__ int lbase[64];
  const int t = threadIdx.x;
  const int qbase = blockIdx.x * 64;
  const int jbase = blockIdx.y * JSPAN;
  const int wv = t >> 6, lane = t & 63, qd = lane >> 4, l16 = lane & 15;
  const int mi = (wv & 3) * 16, ni = (wv >> 2) * 16;

  if (t < 64) lcnt[t] = 0;

  bf16x8 ah[KC], al[KC];
  {
    const int arow = qbase + mi + l16;
    const int akey = arow & (CH - 1);
    #pragma unroll
    for (int kc = 0; kc < KC; kc++) {
      size_t o = (size_t)arow * C + (size_t)(((kc * 4 + qd) ^ akey) * 8);
      ah[kc] = *(const bf16x8*)(xhi + o);
      al[kc] = *(const bf16x8*)(xlo + o);
    }
  }
  int lq[4]; float tq[4];
  #pragma unroll
  for (int r = 0; r < 4; r++) {
    lq[r] = mi + qd * 4 + r;
    tq[r] = tau[qbase + lq[r]];
  }
  const int brow = ni + l16;
  const int bkey = brow & (CH - 1);

  us8 regs[SEGS];
  #pragma unroll
  for (int s = 0; s < SEGS; s++) {
    int boff = (t + s * 512) * 16;
    int mtx = boff >= NB;
    int off = boff & (NB - 1);
    regs[s] = *(const us8*)((mtx ? xlo : xhi) + (size_t)jbase * C + off / 2);
  }
  for (int ti = 0; ti < JSPAN / 32; ti++) {
    __syncthreads();                      // also covers lcnt init at ti==0
    #pragma unroll
    for (int s = 0; s < SEGS; s++) {
      int boff = (t + s * 512) * 16;
      int mtx = boff >= NB;
      int off = boff & (NB - 1);
      *(us8*)&Bs[mtx * NB + off] = regs[s];
    }
    __syncthreads();
    if (ti + 1 < JSPAN / 32) {
      #pragma unroll
      for (int s = 0; s < SEGS; s++) {
        int boff = (t + s * 512) * 16;
        int mtx = boff >= NB;
        int off = boff & (NB - 1);
        regs[s] = *(const us8*)((mtx ? xlo : xhi) + (size_t)(jbase + (ti + 1) * 32) * C + off / 2);
      }
    }
    f32x4 acc = {0.f, 0.f, 0.f, 0.f};
    #pragma unroll
    for (int kc = 0; kc < KC; kc++) {
      size_t bo = (size_t)brow * (2 * C) + (size_t)(((kc * 4 + qd) ^ bkey) * 16);
      bf16x8 bh = *(const bf16x8*)&Bs[bo];
      bf16x8 bl = *(const bf16x8*)&Bs[NB + bo];
      acc = __builtin_amdgcn_mfma_f32_16x16x32_bf16(ah[kc], bh, acc, 0, 0, 0);
      acc = __builtin_amdgcn_mfma_f32_16x16x32_bf16(ah[kc], bl, acc, 0, 0, 0);
      acc = __builtin_amdgcn_mfma_f32_16x16x32_bf16(al[kc], bh, acc, 0, 0, 0);
    }
    const int j = jbase + ti * 32 + ni + l16;
    const float sj = sq[j];
    #pragma unroll
    for (int r = 0; r < 4; r++) {
      float d = fmaf(-2.f, acc[r], sj);
      if (d <= tq[r] && j != qbase + lq[r]) {
        int pos = atomicAdd(&lcnt[lq[r]], 1);
        if (pos < LBUF) {
          lbuf[lq[r] * LBUF + pos] = j;
        } else {                          // rare overflow: direct global append
          int gp = atomicAdd(&cnt[qbase + lq[r]], 1);
          if (gp < CAP) list[(size_t)(qbase + lq[r]) * CAP + gp] = j;
        }
      }
    }
  }
  __syncthreads();
  if (t < 64) {
    int c = lcnt[t]; if (c > LBUF) c = LBUF;
    lcnt[t] = c;
    lbase[t] = atomicAdd(&cnt[qbase + t], c);
  }
  __syncthreads();
  for (int v = t; v < 64 * LBUF; v += 512) {
    int q = v >> 7, e = v & (LBUF - 1);   // LBUF == 128
    if (e < lcnt[q]) {
      int p = lbase[q] + e;
      if (p < CAP) list[(size_t)(qbase + q) * CAP + p] = lbuf[v];
    }
  }
}

__global__ void zero_cnt_kernel(int* __restrict__ cnt) {
  cnt[blockIdx.x * 256 + threadIdx.x] = 0;
}

// ---------------------------------------------------------------------------
// KNN refine v3 (np-fp32-exact, arithmetic unchanged): smaller LDS chunk
// (32 rows for C=128, 64 for C=64) -> block LDS ~21.5 KB -> ~7 blocks/CU
// (was ~4 at 38.4 KB). More chunks/barriers, but 2x resident blocks hide the
// serial stage+dependent-chain latency. Candidate sets, formulas, ranking
// identical -> output bit-identical.
template<int C>
__launch_bounds__(256)
__global__ void knn_refine_np(const float* __restrict__ feat, const float* __restrict__ sq,
                              const int* __restrict__ cnt, const int* __restrict__ list,
                              int* __restrict__ idx_out) {
  constexpr int CHUNK = (C == 64) ? 64 : 32;
  __shared__ float rows[CHUNK * (C + 1)];
  __shared__ float xqs[C];
  __shared__ float ds[CAP];
  __shared__ int   js[CAP];
  __shared__ int   jl[CHUNK];
  __shared__ float sjl[CHUNK];
  const int q = blockIdx.x;
  const int t = threadIdx.x;  // 256
  for (int v = t; v < C; v += 256) xqs[v] = feat[(size_t)q * C + v];
  int cq = cnt[q]; if (cq > CAP) cq = CAP;
  const float sqq = sq[q];

  for (int base = 0; base < cq; base += CHUNK) {
    const int nc = (cq - base < CHUNK) ? (cq - base) : CHUNK;
    __syncthreads();                       // jl/rows free (prev chunk done)
    if (t < nc) {
      int j = list[(size_t)q * CAP + base + t];
      jl[t] = j;
      sjl[t] = sq[j];
    }
    __syncthreads();
    for (int v = t; v < nc * C; v += 256) {
      int r = v >> ((C == 64) ? 6 : 7);
      int c = v & (C - 1);
      rows[r * (C + 1) + c] = feat[(size_t)jl[r] * C + c];
    }
    __syncthreads();
    if (t < nc) {
      float g = 0.f;
      const float* row = &rows[t * (C + 1)];
      for (int c = 0; c < C; c++) g = fmaf(xqs[c], row[c], g);
      ds[base + t] = __fsub_rn(__fadd_rn(sqq, sjl[t]), __fmul_rn(2.f, g));
      js[base + t] = jl[t];
    }
  }
  __syncthreads();
  for (int e = t; e < cq; e += 256) {
    float d = ds[e]; int j = js[e];
    int rank = 0;
    for (int m = 0; m < cq; m++) {
      float dm = ds[m]; int jm = js[m];
      if (dm < d || (dm == d && jm < j)) rank++;
    }
    if (rank < KNN_K) idx_out[(size_t)q * KNN_K + rank] = j;
  }
}

// ---------------------------------------------------------------------------
// P[n][ch] = b[ch] + x[n]@(Wtop - Wbot)[:,ch];  Q[n][ch] = x[n]@Wbot[:,ch].
template<int C>
__global__ void pq_kernel(const float* __restrict__ feat, const float* __restrict__ W,
                          const float* __restrict__ b, float* __restrict__ P,
                          float* __restrict__ Q) {
  int gid = blockIdx.x * 256 + threadIdx.x;   // N*128 threads
  int n = gid >> 7, ch = gid & 127;
  const float* xr = feat + (size_t)n * C;
  double p = (double)b[ch], q = 0.0;
  for (int d = 0; d < C; d++) {
    double xv = (double)xr[d];
    p += xv * (double)W[(size_t)d * HDIM + ch];
    q += xv * (double)W[(size_t)(C + d) * HDIM + ch];
  }
  P[gid] = (float)(p - q);
  Q[gid] = (float)q;
}

// ---------------------------------------------------------------------------
__global__ void edge_gather2(const float* __restrict__ P, const float* __restrict__ Q,
                             const int* __restrict__ idx, float* __restrict__ hmax,
                             float* __restrict__ hmin, double* __restrict__ stats) {
  __shared__ double red0[256];
  __shared__ double red1[256];
  const int t = threadIdx.x;
  const int ch = t & 127, half = t >> 7;
  const size_t nb = (size_t)blockIdx.x * 16 + (size_t)half * 8;
  double s = 0.0, s2 = 0.0;
  for (int u = 0; u < 8; u++) {
    const size_t n = nb + u;
    double p = (double)P[n * 128 + ch];
    double mx = -1.0e300, mn = 1.0e300;
    for (int k = 0; k < KNN_K; k++) {
      int j = idx[n * KNN_K + k];
      double h = p + (double)Q[(size_t)j * 128 + ch];
      h = h > 0.0 ? h : 0.0;
      mx = h > mx ? h : mx;
      mn = h < mn ? h : mn;
      s += h; s2 += h * h;
    }
    hmax[n * 128 + ch] = (float)mx;
    hmin[n * 128 + ch] = (float)mn;
  }
  red0[t] = s; red1[t] = s2;
  __syncthreads();
  if (t < 128) {
    atomicAdd(&stats[ch],       red0[t] + red0[t + 128]);
    atomicAdd(&stats[128 + ch], red1[t] + red1[t + 128]);
  }
}

__global__ void zero_stats_d(double* __restrict__ stats) {
  stats[threadIdx.x] = 0.0;
}

__global__ void bn_finalize_d(const double* __restrict__ stats, const float* __restrict__ g,
                              const float* __restrict__ beta, double* __restrict__ ss) {
  int ch = threadIdx.x;
  const double inv = 1.0 / ((double)N_PTS * (double)KNN_K);
  double mu = stats[ch] * inv;
  double var = stats[128 + ch] * inv - mu * mu;
  double sc = (double)g[ch] / sqrt(var + 1e-5);
  ss[ch] = sc;
  ss[128 + ch] = (double)beta[ch] - mu * sc;
}

__global__ void ec_out_d(const float* __restrict__ hmax, const float* __restrict__ hmin,
                         const double* __restrict__ ss, float* __restrict__ h_f) {
  size_t i = (size_t)blockIdx.x * 256 + threadIdx.x;
  int ch = (int)(i & 127);
  double sc = ss[ch];
  double v = sc >= 0.0 ? (double)hmax[i] : (double)hmin[i];
  h_f[i] = (float)(v * sc + ss[128 + ch]);
}

// ---------------------------------------------------------------------------
__global__ void head1_kernel(const float* __restrict__ h2, const float* __restrict__ lw1,
                             const float* __restrict__ lb1, float* __restrict__ T) {
  int gid = blockIdx.x * 256 + threadIdx.x;
  int n = gid >> 6, hc = gid & 63;
  const float* hr = h2 + (size_t)n * 128;
  double a = (double)lb1[hc];
  for (int d = 0; d < 128; d++) {
    double v = (double)hr[d];
    v = v > 0.0 ? v : 0.0;
    a += v * (double)lw1[(size_t)d * 64 + hc];
  }
  T[gid] = (float)(a > 0.0 ? a : 0.0);
}

__global__ void head2_kernel(const float* __restrict__ T, const float* __restrict__ lw2,
                             const float* __restrict__ lb2, float* __restrict__ out) {
  int gid = blockIdx.x * 256 + threadIdx.x;
  int n = gid >> 6, oc = gid & 63;
  const float* tr = T + (size_t)n * 64;
  double a = (double)lb2[oc];
  for (int d = 0; d < 64; d++) a += (double)tr[d] * (double)lw2[(size_t)d * 64 + oc];
  out[gid] = (float)a;
}

// ---------------------------------------------------------------------------
extern "C" void kernel_launch(void* const* d_in, const int* in_sizes, int n_in,
                              void* d_out, int out_size, void* d_ws, size_t ws_size,
                              hipStream_t stream) {
  (void)in_sizes; (void)n_in; (void)out_size; (void)ws_size;
  const float* x     = (const float*)d_in[0];
  const float* W1    = (const float*)d_in[1];
  const float* b1    = (const float*)d_in[2];
  const float* g1    = (const float*)d_in[3];
  const float* beta1 = (const float*)d_in[4];
  const float* W2    = (const float*)d_in[5];
  const float* b2    = (const float*)d_in[6];
  const float* g2    = (const float*)d_in[7];
  const float* beta2 = (const float*)d_in[8];
  const float* lw1   = (const float*)d_in[9];
  const float* lb1   = (const float*)d_in[10];
  const float* lw2   = (const float*)d_in[11];
  const float* lb2   = (const float*)d_in[12];
  float* out = (float*)d_out;

  char* w = (char*)d_ws;
  size_t off = 0;
  auto alloc = [&](size_t bytes) { char* p = w + off; off += (bytes + 255) & ~(size_t)255; return p; };
  float*  sq    = (float*) alloc(N_PTS * 4);
  float*  tau   = (float*) alloc(N_PTS * 4);
  int*    cnt   = (int*)   alloc(N_PTS * 4);
  int*    list  = (int*)   alloc((size_t)N_PTS * CAP * 4);      // 32 MB
  int*    idx   = (int*)   alloc((size_t)N_PTS * KNN_K * 4);    //  2 MB
  unsigned short* xhi = (unsigned short*)alloc((size_t)N_PTS * HDIM * 2);
  unsigned short* xlo = (unsigned short*)alloc((size_t)N_PTS * HDIM * 2);
  float*  P     = (float*) alloc((size_t)N_PTS * HDIM * 4);
  float*  Q     = (float*) alloc((size_t)N_PTS * HDIM * 4);
  float*  hmax  = (float*) alloc((size_t)N_PTS * HDIM * 4);
  float*  hmin  = (float*) alloc((size_t)N_PTS * HDIM * 4);
  double* stats = (double*)alloc(2 * HDIM * 8);
  double* ss    = (double*)alloc(2 * HDIM * 8);
  float*  h1f   = (float*) alloc((size_t)N_PTS * HDIM * 4);
  float*  h2f   = P;        // reuse (P dead after gather2)
  float*  T     = Q;        // reuse (Q dead after gather2)

  // ---- stage 1: knn on x (C=64) ----
  sqnorm_np_kernel<64><<<N_PTS / 256, 256, 0, stream>>>(x, sq);
  split_swz_kernel<64><<<N_PTS * 8 / 256, 256, 0, stream>>>(x, xhi, xlo);
  knn_tau<64><<<N_PTS / 64, 512, 0, stream>>>(xhi, xlo, sq, 0.05f, tau);
  zero_cnt_kernel<<<N_PTS / 256, 256, 0, stream>>>(cnt);
  knn_filter<64><<<dim3(N_PTS / 64, NSLICE), 512, 0, stream>>>(xhi, xlo, sq, tau, cnt, list);
  knn_refine_np<64><<<N_PTS, 256, 0, stream>>>(x, sq, cnt, list, idx);

  // ---- edge conv 1 (fp64) ----
  pq_kernel<64><<<N_PTS * 128 / 256, 256, 0, stream>>>(x, W1, b1, P, Q);
  zero_stats_d<<<1, 256, 0, stream>>>(stats);
  edge_gather2<<<N_PTS / 16, 256, 0, stream>>>(P, Q, idx, hmax, hmin, stats);
  bn_finalize_d<<<1, 128, 0, stream>>>(stats, g1, beta1, ss);
  ec_out_d<<<N_PTS * HDIM / 256, 256, 0, stream>>>(hmax, hmin, ss, h1f);

  // ---- stage 2: knn on h1 (C=128) ----
  sqnorm_np_kernel<128><<<N_PTS / 256, 256, 0, stream>>>(h1f, sq);
  split_swz_kernel<128><<<N_PTS * 16 / 256, 256, 0, stream>>>(h1f, xhi, xlo);
  knn_tau<128><<<N_PTS / 64, 512, 0, stream>>>(xhi, xlo, sq, 0.2f, tau);
  zero_cnt_kernel<<<N_PTS / 256, 256, 0, stream>>>(cnt);
  knn_filter<128><<<dim3(N_PTS / 64, NSLICE), 512, 0, stream>>>(xhi, xlo, sq, tau, cnt, list);
  knn_refine_np<128><<<N_PTS, 256, 0, stream>>>(h1f, sq, cnt, list, idx);

  // ---- edge conv 2 (fp64) ----
  pq_kernel<128><<<N_PTS * 128 / 256, 256, 0, stream>>>(h1f, W2, b2, P, Q);
  zero_stats_d<<<1, 256, 0, stream>>>(stats);
  edge_gather2<<<N_PTS / 16, 256, 0, stream>>>(P, Q, idx, hmax, hmin, stats);
  bn_finalize_d<<<1, 128, 0, stream>>>(stats, g2, beta2, ss);
  ec_out_d<<<N_PTS * HDIM / 256, 256, 0, stream>>>(hmax, hmin, ss, h2f);

  // ---- head (fp64) ----
  head1_kernel<<<N_PTS * 64 / 256, 256, 0, stream>>>(h2f, lw1, lb1, T);
  head2_kernel<<<N_PTS * 64 / 256, 256, 0, stream>>>(T, lw2, lb2, out);
}

// Round 13
// 1330.675 us; speedup vs baseline: 1.8630x; 1.2202x over previous
//
#include <hip/hip_runtime.h>
#include <hip/hip_bf16.h>
#include <math.h>

#define N_PTS 16384
#define KNN_K 32
#define CAP 512            // per-query filtered candidate list capacity
#define HDIM 128
#define TSAMP 4096         // tau sample: first TSAMP rows (subset order-stat bound)
#define NSLICE 4
#define LBUF 64            // per-query LDS hit buffer (per slice-block), now pairs

typedef __attribute__((ext_vector_type(8))) short bf16x8;
typedef __attribute__((ext_vector_type(8))) unsigned short us8;
typedef __attribute__((ext_vector_type(4))) float f32x4;

// ---------------------------------------------------------------------------
// numpy-pairwise fp32 sum of squares per row (np.sum(x*x, axis=1) replica).
template<int C>
__global__ void sqnorm_np_kernel(const float* __restrict__ feat, float* __restrict__ sq) {
  int r = blockIdx.x * 256 + threadIdx.x;
  if (r >= N_PTS) return;
  const float* xr = feat + (size_t)r * C;
  float acc[8];
  #pragma unroll
  for (int j = 0; j < 8; j++) acc[j] = __fmul_rn(xr[j], xr[j]);
  for (int i = 8; i < C; i += 8) {
    #pragma unroll
    for (int j = 0; j < 8; j++)
      acc[j] = __fadd_rn(acc[j], __fmul_rn(xr[i + j], xr[i + j]));
  }
  float s01 = __fadd_rn(acc[0], acc[1]);
  float s23 = __fadd_rn(acc[2], acc[3]);
  float s45 = __fadd_rn(acc[4], acc[5]);
  float s67 = __fadd_rn(acc[6], acc[7]);
  sq[r] = __fadd_rn(__fadd_rn(s01, s23), __fadd_rn(s45, s67));
}

// ---------------------------------------------------------------------------
// hi/lo bf16 split with XOR chunk swizzle baked into the global layout.
template<int C>
__global__ void split_swz_kernel(const float* __restrict__ x, unsigned short* __restrict__ hi,
                                 unsigned short* __restrict__ lo) {
  constexpr int CH = C / 8;
  int gid = blockIdx.x * 256 + threadIdx.x;    // N*CH threads
  int n = gid / CH, c = gid & (CH - 1);
  if (n >= N_PTS) return;
  const float* src = x + (size_t)n * C + c * 8;
  unsigned short h8[8], l8[8];
  #pragma unroll
  for (int j = 0; j < 8; j++) {
    float v = src[j];
    __hip_bfloat16 h = __float2bfloat16(v);
    float hf = __bfloat162float(h);
    __hip_bfloat16 l = __float2bfloat16(v - hf);
    h8[j] = *(unsigned short*)&h;
    l8[j] = *(unsigned short*)&l;
  }
  size_t o = (size_t)n * C + (size_t)(((c ^ (n & (CH - 1)))) * 8);
  *(us8*)(hi + o) = *(const us8*)h8;
  *(us8*)(lo + o) = *(const us8*)l8;
}

// ---------------------------------------------------------------------------
// KNN pass A (tau, sampled) — unchanged (known good).
template<int C>
__launch_bounds__(512)
__global__ void knn_tau(const unsigned short* __restrict__ xhi,
                        const unsigned short* __restrict__ xlo,
                        const float* __restrict__ sq,
                        float margin, float* __restrict__ tau) {
  constexpr int CH = C / 8, KC = C / 32;
  constexpr int NB = 32 * C * 2;
  constexpr int SEGS = (2 * NB) / 16 / 512;
  __shared__ unsigned char Bs[2 * NB];
  __shared__ float tred[64][65];
  const int t = threadIdx.x;
  const int qbase = blockIdx.x * 64;
  const int wv = t >> 6, lane = t & 63, qd = lane >> 4, l16 = lane & 15;
  const int mi = (wv & 3) * 16, ni = (wv >> 2) * 16;

  bf16x8 ah[KC], al[KC];
  {
    const int arow = qbase + mi + l16;
    const int akey = arow & (CH - 1);
    #pragma unroll
    for (int kc = 0; kc < KC; kc++) {
      size_t o = (size_t)arow * C + (size_t)(((kc * 4 + qd) ^ akey) * 8);
      ah[kc] = *(const bf16x8*)(xhi + o);
      al[kc] = *(const bf16x8*)(xlo + o);
    }
  }
  int qr[4];
  #pragma unroll
  for (int r = 0; r < 4; r++) qr[r] = qbase + mi + qd * 4 + r;
  float t0[4], t1[4];
  #pragma unroll
  for (int r = 0; r < 4; r++) { t0[r] = INFINITY; t1[r] = INFINITY; }

  const int brow = ni + l16;
  const int bkey = brow & (CH - 1);

  us8 regs[SEGS];
  #pragma unroll
  for (int s = 0; s < SEGS; s++) {
    int boff = (t + s * 512) * 16;
    int mtx = boff >= NB;
    int off = boff & (NB - 1);
    regs[s] = *(const us8*)((mtx ? xlo : xhi) + off / 2);
  }
  for (int ti = 0; ti < TSAMP / 32; ti++) {
    __syncthreads();
    #pragma unroll
    for (int s = 0; s < SEGS; s++) {
      int boff = (t + s * 512) * 16;
      int mtx = boff >= NB;
      int off = boff & (NB - 1);
      *(us8*)&Bs[mtx * NB + off] = regs[s];
    }
    __syncthreads();
    if (ti + 1 < TSAMP / 32) {
      #pragma unroll
      for (int s = 0; s < SEGS; s++) {
        int boff = (t + s * 512) * 16;
        int mtx = boff >= NB;
        int off = boff & (NB - 1);
        regs[s] = *(const us8*)((mtx ? xlo : xhi) + (size_t)(ti + 1) * 32 * C + off / 2);
      }
    }
    f32x4 acc = {0.f, 0.f, 0.f, 0.f};
    #pragma unroll
    for (int kc = 0; kc < KC; kc++) {
      size_t bo = (size_t)brow * (2 * C) + (size_t)(((kc * 4 + qd) ^ bkey) * 16);
      bf16x8 bh = *(const bf16x8*)&Bs[bo];
      bf16x8 bl = *(const bf16x8*)&Bs[NB + bo];
      acc = __builtin_amdgcn_mfma_f32_16x16x32_bf16(ah[kc], bh, acc, 0, 0, 0);
      acc = __builtin_amdgcn_mfma_f32_16x16x32_bf16(ah[kc], bl, acc, 0, 0, 0);
      acc = __builtin_amdgcn_mfma_f32_16x16x32_bf16(al[kc], bh, acc, 0, 0, 0);
    }
    const int j = ti * 32 + ni + l16;
    const float sj = sq[j];
    #pragma unroll
    for (int r = 0; r < 4; r++) {
      float d = fmaf(-2.f, acc[r], sj);
      if (d < t1[r] && j != qr[r]) {
        bool lt = d < t0[r];
        t1[r] = lt ? t0[r] : d;
        t0[r] = lt ? d : t0[r];
      }
    }
  }
  const int strm = ni + l16;
  #pragma unroll
  for (int r = 0; r < 4; r++) {
    tred[mi + qd * 4 + r][strm]      = t0[r];
    tred[mi + qd * 4 + r][32 + strm] = t1[r];
  }
  __syncthreads();
  const int tq = t >> 3, i0 = (t & 7) * 8;
  #pragma unroll
  for (int ii = 0; ii < 8; ii++) {
    const int i = i0 + ii;
    const float vi = tred[tq][i];
    int rank = 0;
    for (int m = 0; m < 64; m++) {
      float vm = tred[tq][m];
      rank += (vm < vi || (vm == vi && m < i)) ? 1 : 0;
    }
    if (rank == 32) tau[qbase + tq] = vi + margin;
  }
}

// ---------------------------------------------------------------------------
// KNN pass B (filter v4): as round 11/12 (LDS-atomic hit buffers) but stores
// (j, d_split) PAIRS so the refine can window on d_split without gathers.
template<int C>
__launch_bounds__(512)
__global__ void knn_filter(const unsigned short* __restrict__ xhi,
                           const unsigned short* __restrict__ xlo,
                           const float* __restrict__ sq,
                           const float* __restrict__ tau,
                           int* __restrict__ cnt, int* __restrict__ list_j,
                           float* __restrict__ list_d) {
  constexpr int CH = C / 8, KC = C / 32;
  constexpr int NB = 32 * C * 2;
  constexpr int SEGS = (2 * NB) / 16 / 512;
  constexpr int JSPAN = N_PTS / NSLICE;
  __shared__ unsigned char Bs[2 * NB];
  __shared__ int   lbj[64 * LBUF];      // 16 KB
  __shared__ float lbd[64 * LBUF];      // 16 KB
  __shared__ int lcnt[64];
  __shared__ int lbase[64];
  const int t = threadIdx.x;
  const int qbase = blockIdx.x * 64;
  const int jbase = blockIdx.y * JSPAN;
  const int wv = t >> 6, lane = t & 63, qd = lane >> 4, l16 = lane & 15;
  const int mi = (wv & 3) * 16, ni = (wv >> 2) * 16;

  if (t < 64) lcnt[t] = 0;

  bf16x8 ah[KC], al[KC];
  {
    const int arow = qbase + mi + l16;
    const int akey = arow & (CH - 1);
    #pragma unroll
    for (int kc = 0; kc < KC; kc++) {
      size_t o = (size_t)arow * C + (size_t)(((kc * 4 + qd) ^ akey) * 8);
      ah[kc] = *(const bf16x8*)(xhi + o);
      al[kc] = *(const bf16x8*)(xlo + o);
    }
  }
  int lq[4]; float tq[4];
  #pragma unroll
  for (int r = 0; r < 4; r++) {
    lq[r] = mi + qd * 4 + r;
    tq[r] = tau[qbase + lq[r]];
  }
  const int brow = ni + l16;
  const int bkey = brow & (CH - 1);

  us8 regs[SEGS];
  #pragma unroll
  for (int s = 0; s < SEGS; s++) {
    int boff = (t + s * 512) * 16;
    int mtx = boff >= NB;
    int off = boff & (NB - 1);
    regs[s] = *(const us8*)((mtx ? xlo : xhi) + (size_t)jbase * C + off / 2);
  }
  for (int ti = 0; ti < JSPAN / 32; ti++) {
    __syncthreads();                      // also covers lcnt init at ti==0
    #pragma unroll
    for (int s = 0; s < SEGS; s++) {
      int boff = (t + s * 512) * 16;
      int mtx = boff >= NB;
      int off = boff & (NB - 1);
      *(us8*)&Bs[mtx * NB + off] = regs[s];
    }
    __syncthreads();
    if (ti + 1 < JSPAN / 32) {
      #pragma unroll
      for (int s = 0; s < SEGS; s++) {
        int boff = (t + s * 512) * 16;
        int mtx = boff >= NB;
        int off = boff & (NB - 1);
        regs[s] = *(const us8*)((mtx ? xlo : xhi) + (size_t)(jbase + (ti + 1) * 32) * C + off / 2);
      }
    }
    f32x4 acc = {0.f, 0.f, 0.f, 0.f};
    #pragma unroll
    for (int kc = 0; kc < KC; kc++) {
      size_t bo = (size_t)brow * (2 * C) + (size_t)(((kc * 4 + qd) ^ bkey) * 16);
      bf16x8 bh = *(const bf16x8*)&Bs[bo];
      bf16x8 bl = *(const bf16x8*)&Bs[NB + bo];
      acc = __builtin_amdgcn_mfma_f32_16x16x32_bf16(ah[kc], bh, acc, 0, 0, 0);
      acc = __builtin_amdgcn_mfma_f32_16x16x32_bf16(ah[kc], bl, acc, 0, 0, 0);
      acc = __builtin_amdgcn_mfma_f32_16x16x32_bf16(al[kc], bh, acc, 0, 0, 0);
    }
    const int j = jbase + ti * 32 + ni + l16;
    const float sj = sq[j];
    #pragma unroll
    for (int r = 0; r < 4; r++) {
      float d = fmaf(-2.f, acc[r], sj);
      if (d <= tq[r] && j != qbase + lq[r]) {
        int pos = atomicAdd(&lcnt[lq[r]], 1);
        if (pos < LBUF) {
          lbj[lq[r] * LBUF + pos] = j;
          lbd[lq[r] * LBUF + pos] = d;
        } else {                          // rare overflow: direct global append
          int gp = atomicAdd(&cnt[qbase + lq[r]], 1);
          if (gp < CAP) {
            list_j[(size_t)(qbase + lq[r]) * CAP + gp] = j;
            list_d[(size_t)(qbase + lq[r]) * CAP + gp] = d;
          }
        }
      }
    }
  }
  __syncthreads();
  if (t < 64) {
    int c = lcnt[t]; if (c > LBUF) c = LBUF;
    lcnt[t] = c;
    lbase[t] = atomicAdd(&cnt[qbase + t], c);
  }
  __syncthreads();
  for (int v = t; v < 64 * LBUF; v += 512) {
    int q = v / LBUF, e = v % LBUF;
    if (e < lcnt[q]) {
      int p = lbase[q] + e;
      if (p < CAP) {
        list_j[(size_t)(qbase + q) * CAP + p] = lbj[v];
        list_d[(size_t)(qbase + q) * CAP + p] = lbd[v];
      }
    }
  }
}

__global__ void zero_cnt_kernel(int* __restrict__ cnt) {
  cnt[blockIdx.x * 256 + threadIdx.x] = 0;
}

// ---------------------------------------------------------------------------
// KNN refine v4 (np-fp32-exact winners, windowed): rank candidates by their
// stored split-bf16 d (zero gathers), find the 32nd-smallest (cut), then
// np-score ONLY the window {d_split <= cut + WMARG}. WMARG = validated tau
// margin >= 2*|d_split - d_np| sup-norm, so window contains the np-top-32
// (order-statistic shift bound), and all winners get exact np scores+order.
template<int C>
__launch_bounds__(256)
__global__ void knn_refine_np(const float* __restrict__ feat, const float* __restrict__ sq,
                              const int* __restrict__ cnt, const int* __restrict__ list_j,
                              const float* __restrict__ list_d, float wmarg,
                              int* __restrict__ idx_out) {
  __shared__ float ds[CAP];
  __shared__ int   js[CAP];
  __shared__ int   widx[CAP];
  __shared__ float dnp[CAP];
  __shared__ float xqs[C];
  __shared__ float rows[32 * (C + 1)];
  __shared__ int   jl[32];
  __shared__ float sjl[32];
  __shared__ float cutd;
  __shared__ int   wn;
  const int q = blockIdx.x;
  const int t = threadIdx.x;  // 256
  for (int v = t; v < C; v += 256) xqs[v] = feat[(size_t)q * C + v];
  int cq = cnt[q]; if (cq > CAP) cq = CAP;
  const float sqq = sq[q];
  if (t == 0) { wn = 0; cutd = INFINITY; }
  for (int e = t; e < cq; e += 256) {
    js[e] = list_j[(size_t)q * CAP + e];
    ds[e] = list_d[(size_t)q * CAP + e];
  }
  __syncthreads();
  // cut = 32nd smallest by (d_split, j); unique writer via strict total order
  if (cq > KNN_K) {
    for (int e = t; e < cq; e += 256) {
      float d = ds[e]; int j = js[e];
      int rank = 0;
      for (int m = 0; m < cq; m++) {
        float dm = ds[m]; int jm = js[m];
        rank += (dm < d || (dm == d && jm < j)) ? 1 : 0;
      }
      if (rank == KNN_K - 1) cutd = d;
    }
  }
  __syncthreads();
  const float wcut = cutd + wmarg;
  for (int e = t; e < cq; e += 256)
    if (ds[e] <= wcut) { int p = atomicAdd(&wn, 1); widx[p] = e; }
  __syncthreads();
  const int nw = wn;        // <= cq <= CAP, no overflow possible
  // np-score window in chunks of 32 (identical fp32 chain to prior rounds)
  for (int base = 0; base < nw; base += 32) {
    const int nc = (nw - base < 32) ? (nw - base) : 32;
    __syncthreads();
    if (t < nc) {
      int j = js[widx[base + t]];
      jl[t] = j;
      sjl[t] = sq[j];
    }
    __syncthreads();
    for (int v = t; v < nc * C; v += 256) {
      int r = v >> ((C == 64) ? 6 : 7);
      int c = v & (C - 1);
      rows[r * (C + 1) + c] = feat[(size_t)jl[r] * C + c];
    }
    __syncthreads();
    if (t < nc) {
      float g = 0.f;
      const float* row = &rows[t * (C + 1)];
      for (int c = 0; c < C; c++) g = fmaf(xqs[c], row[c], g);
      dnp[base + t] = __fsub_rn(__fadd_rn(sqq, sjl[t]), __fmul_rn(2.f, g));
    }
  }
  __syncthreads();
  for (int e = t; e < nw; e += 256) {
    float d = dnp[e]; int j = js[widx[e]];
    int rank = 0;
    for (int m = 0; m < nw; m++) {
      float dm = dnp[m]; int jm = js[widx[m]];
      rank += (dm < d || (dm == d && jm < j)) ? 1 : 0;
    }
    if (rank < KNN_K) idx_out[(size_t)q * KNN_K + rank] = j;
  }
}

// ---------------------------------------------------------------------------
// P[n][ch] = b[ch] + x[n]@(Wtop - Wbot)[:,ch];  Q[n][ch] = x[n]@Wbot[:,ch].
template<int C>
__global__ void pq_kernel(const float* __restrict__ feat, const float* __restrict__ W,
                          const float* __restrict__ b, float* __restrict__ P,
                          float* __restrict__ Q) {
  int gid = blockIdx.x * 256 + threadIdx.x;   // N*128 threads
  int n = gid >> 7, ch = gid & 127;
  const float* xr = feat + (size_t)n * C;
  double p = (double)b[ch], q = 0.0;
  for (int d = 0; d < C; d++) {
    double xv = (double)xr[d];
    p += xv * (double)W[(size_t)d * HDIM + ch];
    q += xv * (double)W[(size_t)(C + d) * HDIM + ch];
  }
  P[gid] = (float)(p - q);
  Q[gid] = (float)q;
}

// ---------------------------------------------------------------------------
__global__ void edge_gather2(const float* __restrict__ P, const float* __restrict__ Q,
                             const int* __restrict__ idx, float* __restrict__ hmax,
                             float* __restrict__ hmin, double* __restrict__ stats) {
  __shared__ double red0[256];
  __shared__ double red1[256];
  const int t = threadIdx.x;
  const int ch = t & 127, half = t >> 7;
  const size_t nb = (size_t)blockIdx.x * 16 + (size_t)half * 8;
  double s = 0.0, s2 = 0.0;
  for (int u = 0; u < 8; u++) {
    const size_t n = nb + u;
    double p = (double)P[n * 128 + ch];
    double mx = -1.0e300, mn = 1.0e300;
    for (int k = 0; k < KNN_K; k++) {
      int j = idx[n * KNN_K + k];
      double h = p + (double)Q[(size_t)j * 128 + ch];
      h = h > 0.0 ? h : 0.0;
      mx = h > mx ? h : mx;
      mn = h < mn ? h : mn;
      s += h; s2 += h * h;
    }
    hmax[n * 128 + ch] = (float)mx;
    hmin[n * 128 + ch] = (float)mn;
  }
  red0[t] = s; red1[t] = s2;
  __syncthreads();
  if (t < 128) {
    atomicAdd(&stats[ch],       red0[t] + red0[t + 128]);
    atomicAdd(&stats[128 + ch], red1[t] + red1[t + 128]);
  }
}

__global__ void zero_stats_d(double* __restrict__ stats) {
  stats[threadIdx.x] = 0.0;
}

__global__ void bn_finalize_d(const double* __restrict__ stats, const float* __restrict__ g,
                              const float* __restrict__ beta, double* __restrict__ ss) {
  int ch = threadIdx.x;
  const double inv = 1.0 / ((double)N_PTS * (double)KNN_K);
  double mu = stats[ch] * inv;
  double var = stats[128 + ch] * inv - mu * mu;
  double sc = (double)g[ch] / sqrt(var + 1e-5);
  ss[ch] = sc;
  ss[128 + ch] = (double)beta[ch] - mu * sc;
}

__global__ void ec_out_d(const float* __restrict__ hmax, const float* __restrict__ hmin,
                         const double* __restrict__ ss, float* __restrict__ h_f) {
  size_t i = (size_t)blockIdx.x * 256 + threadIdx.x;
  int ch = (int)(i & 127);
  double sc = ss[ch];
  double v = sc >= 0.0 ? (double)hmax[i] : (double)hmin[i];
  h_f[i] = (float)(v * sc + ss[128 + ch]);
}

// ---------------------------------------------------------------------------
__global__ void head1_kernel(const float* __restrict__ h2, const float* __restrict__ lw1,
                             const float* __restrict__ lb1, float* __restrict__ T) {
  int gid = blockIdx.x * 256 + threadIdx.x;
  int n = gid >> 6, hc = gid & 63;
  const float* hr = h2 + (size_t)n * 128;
  double a = (double)lb1[hc];
  for (int d = 0; d < 128; d++) {
    double v = (double)hr[d];
    v = v > 0.0 ? v : 0.0;
    a += v * (double)lw1[(size_t)d * 64 + hc];
  }
  T[gid] = (float)(a > 0.0 ? a : 0.0);
}

__global__ void head2_kernel(const float* __restrict__ T, const float* __restrict__ lw2,
                             const float* __restrict__ lb2, float* __restrict__ out) {
  int gid = blockIdx.x * 256 + threadIdx.x;
  int n = gid >> 6, oc = gid & 63;
  const float* tr = T + (size_t)n * 64;
  double a = (double)lb2[oc];
  for (int d = 0; d < 64; d++) a += (double)tr[d] * (double)lw2[(size_t)d * 64 + oc];
  out[gid] = (float)a;
}

// ---------------------------------------------------------------------------
extern "C" void kernel_launch(void* const* d_in, const int* in_sizes, int n_in,
                              void* d_out, int out_size, void* d_ws, size_t ws_size,
                              hipStream_t stream) {
  (void)in_sizes; (void)n_in; (void)out_size; (void)ws_size;
  const float* x     = (const float*)d_in[0];
  const float* W1    = (const float*)d_in[1];
  const float* b1    = (const float*)d_in[2];
  const float* g1    = (const float*)d_in[3];
  const float* beta1 = (const float*)d_in[4];
  const float* W2    = (const float*)d_in[5];
  const float* b2    = (const float*)d_in[6];
  const float* g2    = (const float*)d_in[7];
  const float* beta2 = (const float*)d_in[8];
  const float* lw1   = (const float*)d_in[9];
  const float* lb1   = (const float*)d_in[10];
  const float* lw2   = (const float*)d_in[11];
  const float* lb2   = (const float*)d_in[12];
  float* out = (float*)d_out;

  char* w = (char*)d_ws;
  size_t off = 0;
  auto alloc = [&](size_t bytes) { char* p = w + off; off += (bytes + 255) & ~(size_t)255; return p; };
  float*  sq     = (float*) alloc(N_PTS * 4);
  float*  tau    = (float*) alloc(N_PTS * 4);
  int*    cnt    = (int*)   alloc(N_PTS * 4);
  int*    list_j = (int*)   alloc((size_t)N_PTS * CAP * 4);     // 32 MB
  float*  list_d = (float*) alloc((size_t)N_PTS * CAP * 4);     // 32 MB
  int*    idx    = (int*)   alloc((size_t)N_PTS * KNN_K * 4);   //  2 MB
  unsigned short* xhi = (unsigned short*)alloc((size_t)N_PTS * HDIM * 2);
  unsigned short* xlo = (unsigned short*)alloc((size_t)N_PTS * HDIM * 2);
  float*  P      = (float*) alloc((size_t)N_PTS * HDIM * 4);
  float*  Q      = (float*) alloc((size_t)N_PTS * HDIM * 4);
  float*  hmax   = (float*) alloc((size_t)N_PTS * HDIM * 4);
  float*  hmin   = (float*) alloc((size_t)N_PTS * HDIM * 4);
  double* stats  = (double*)alloc(2 * HDIM * 8);
  double* ss     = (double*)alloc(2 * HDIM * 8);
  float*  h1f    = (float*) alloc((size_t)N_PTS * HDIM * 4);
  float*  h2f    = P;       // reuse (P dead after gather2)
  float*  T      = Q;       // reuse (Q dead after gather2)

  // ---- stage 1: knn on x (C=64) ----
  sqnorm_np_kernel<64><<<N_PTS / 256, 256, 0, stream>>>(x, sq);
  split_swz_kernel<64><<<N_PTS * 8 / 256, 256, 0, stream>>>(x, xhi, xlo);
  knn_tau<64><<<N_PTS / 64, 512, 0, stream>>>(xhi, xlo, sq, 0.05f, tau);
  zero_cnt_kernel<<<N_PTS / 256, 256, 0, stream>>>(cnt);
  knn_filter<64><<<dim3(N_PTS / 64, NSLICE), 512, 0, stream>>>(xhi, xlo, sq, tau, cnt, list_j, list_d);
  knn_refine_np<64><<<N_PTS, 256, 0, stream>>>(x, sq, cnt, list_j, list_d, 0.05f, idx);

  // ---- edge conv 1 (fp64) ----
  pq_kernel<64><<<N_PTS * 128 / 256, 256, 0, stream>>>(x, W1, b1, P, Q);
  zero_stats_d<<<1, 256, 0, stream>>>(stats);
  edge_gather2<<<N_PTS / 16, 256, 0, stream>>>(P, Q, idx, hmax, hmin, stats);
  bn_finalize_d<<<1, 128, 0, stream>>>(stats, g1, beta1, ss);
  ec_out_d<<<N_PTS * HDIM / 256, 256, 0, stream>>>(hmax, hmin, ss, h1f);

  // ---- stage 2: knn on h1 (C=128) ----
  sqnorm_np_kernel<128><<<N_PTS / 256, 256, 0, stream>>>(h1f, sq);
  split_swz_kernel<128><<<N_PTS * 16 / 256, 256, 0, stream>>>(h1f, xhi, xlo);
  knn_tau<128><<<N_PTS / 64, 512, 0, stream>>>(xhi, xlo, sq, 0.2f, tau);
  zero_cnt_kernel<<<N_PTS / 256, 256, 0, stream>>>(cnt);
  knn_filter<128><<<dim3(N_PTS / 64, NSLICE), 512, 0, stream>>>(xhi, xlo, sq, tau, cnt, list_j, list_d);
  knn_refine_np<128><<<N_PTS, 256, 0, stream>>>(h1f, sq, cnt, list_j, list_d, 0.2f, idx);

  // ---- edge conv 2 (fp64) ----
  pq_kernel<128><<<N_PTS * 128 / 256, 256, 0, stream>>>(h1f, W2, b2, P, Q);
  zero_stats_d<<<1, 256, 0, stream>>>(stats);
  edge_gather2<<<N_PTS / 16, 256, 0, stream>>>(P, Q, idx, hmax, hmin, stats);
  bn_finalize_d<<<1, 128, 0, stream>>>(stats, g2, beta2, ss);
  ec_out_d<<<N_PTS * HDIM / 256, 256, 0, stream>>>(hmax, hmin, ss, h2f);

  // ---- head (fp64) ----
  head1_kernel<<<N_PTS * 64 / 256, 256, 0, stream>>>(h2f, lw1, lb1, T);
  head2_kernel<<<N_PTS * 64 / 256, 256, 0, stream>>>(T, lw2, lb2, out);
}